// Round 1
// 877.277 us; speedup vs baseline: 2.4760x; 2.4760x over previous
//
#include <hip/hip_runtime.h>
#include <hip/hip_bf16.h>

typedef unsigned int uint32;
typedef unsigned short ushort16;

#define HH 2
#define CC 64
#define DD 64
#define HC 128

__device__ __forceinline__ float bf2f(ushort16 u) {
    union { float f; uint32 u; } x; x.u = ((uint32)u) << 16; return x.f;
}
__device__ __forceinline__ ushort16 f2bf(float f) {
    union { float f; uint32 u; } x; x.f = f;
    uint32 u = x.u;
    u += 0x7FFFu + ((u >> 16) & 1u);   // round-to-nearest-even
    return (ushort16)(u >> 16);
}
__device__ __forceinline__ int clampi(int v, int N) {
    return min(max(v, 0), N - 1);
}

// ---- K0: fold attention vectors into weight matrices ----
__global__ void k_fold(const float* W_lin, const float* att_src,
                       const float* att_dst, const float* W_edge,
                       const float* att_edge, float* vfold) {
    int t = threadIdx.x;            // 128 threads: t = h*64+d
    int h = t >> 6, d = t & 63;
    float vs = 0.f, vd = 0.f, ve = 0.f;
    for (int c = 0; c < CC; c++) {
        float wl = W_lin[d * HC + h * CC + c];
        vs += wl * att_src[h * CC + c];
        vd += wl * att_dst[h * CC + c];
        ve += W_edge[d * HC + h * CC + c] * att_edge[h * CC + c];
    }
    vfold[t] = vs; vfold[128 + t] = vd; vfold[256 + t] = ve;
}

// ---- K1: per-node logits ----
__global__ __launch_bounds__(256) void k_node_logits(
    const float* right, const float* left, const float* vfold,
    float* a_src, float* a_dst, int N)
{
    __shared__ float vs[HC], vd[HC];
    if (threadIdx.x < HC) {
        vs[threadIdx.x] = vfold[threadIdx.x];
        vd[threadIdx.x] = vfold[HC + threadIdx.x];
    }
    __syncthreads();
    int w = threadIdx.x >> 6, lane = threadIdx.x & 63;
    for (int n = blockIdx.x * 4 + w; n < N; n += gridDim.x * 4) {
        float rl = right[(size_t)n * DD + lane];
        float ll = left[(size_t)n * DD + lane];
        float p0 = rl * vs[lane], p1 = rl * vs[64 + lane];
        float q0 = ll * vd[lane], q1 = ll * vd[64 + lane];
        #pragma unroll
        for (int m = 32; m >= 1; m >>= 1) {
            p0 += __shfl_xor(p0, m, 64); p1 += __shfl_xor(p1, m, 64);
            q0 += __shfl_xor(q0, m, 64); q1 += __shfl_xor(q1, m, 64);
        }
        if (lane == 0) {
            a_src[n * 2] = p0; a_src[n * 2 + 1] = p1;
            a_dst[n * 2] = q0; a_dst[n * 2 + 1] = q1;
        }
    }
}

// ---- K2: a_edge GEMV + alpha + leaky-relu -> att_slot (fp32). No atomics. ----
__global__ __launch_bounds__(256) void k_edge_alpha(
    const float* edge_feat, const int* ei, const float* vfold,
    const float* a_src, const float* a_dst,
    float* att_slot, int E, int N)
{
    __shared__ float vE[HC];
    if (threadIdx.x < HC) vE[threadIdx.x] = vfold[256 + threadIdx.x];
    __syncthreads();
    int lane = threadIdx.x & 63;
    int e = blockIdx.x * 4 + (threadIdx.x >> 6);
    if (e >= E) return;
    float fv = edge_feat[(size_t)e * DD + lane];
    float p0 = fv * vE[lane];
    float p1 = fv * vE[64 + lane];
    #pragma unroll
    for (int m = 32; m >= 1; m >>= 1) {
        p0 += __shfl_xor(p0, m, 64); p1 += __shfl_xor(p1, m, 64);
    }
    if (lane == 0) {
        int s  = clampi(ei[e], N);
        int d2 = clampi(ei[E + e], N);
        float al0 = a_src[s * 2]     + a_dst[d2 * 2]     + p0;
        float al1 = a_src[s * 2 + 1] + a_dst[d2 * 2 + 1] + p1;
        al0 = (al0 > 0.f) ? al0 : 0.2f * al0;
        al1 = (al1 > 0.f) ? al1 : 0.2f * al1;
        att_slot[e * 2] = al0; att_slot[e * 2 + 1] = al1;
    }
}

// ---- CSR build: histogram over dst ----
__global__ void k_hist(const int* ei, int* counts, int E, int N) {
    int e = blockIdx.x * 256 + threadIdx.x;
    if (e >= E) return;
    atomicAdd(&counts[clampi(ei[E + e], N)], 1);
}

// ---- scan stage 1: per-block sums of counts ----
__global__ void k_scan1(const int* counts, int* bsum, int N) {
    int idx = blockIdx.x * 256 + threadIdx.x;
    int v = (idx < N) ? counts[idx] : 0;
    #pragma unroll
    for (int m = 32; m >= 1; m >>= 1) v += __shfl_xor(v, m, 64);
    __shared__ int wsum[4];
    if ((threadIdx.x & 63) == 0) wsum[threadIdx.x >> 6] = v;
    __syncthreads();
    if (threadIdx.x == 0) bsum[blockIdx.x] = wsum[0] + wsum[1] + wsum[2] + wsum[3];
}

// ---- scan stage 2: exclusive scan of block sums (NB <= 256) ----
__global__ void k_scan2(const int* bsum, int* bpre, int NB) {
    __shared__ int sh[256];
    int t = threadIdx.x;
    int v = (t < NB) ? bsum[t] : 0;
    sh[t] = v;
    __syncthreads();
    for (int off = 1; off < 256; off <<= 1) {
        int add = (t >= off) ? sh[t - off] : 0;
        __syncthreads();
        sh[t] += add;
        __syncthreads();
    }
    if (t < NB) bpre[t] = sh[t] - v;   // exclusive prefix
}

// ---- scan stage 3: per-element exclusive offsets; init cursor ----
__global__ void k_scan3(const int* counts, const int* bpre,
                        int* offs, int* cursor, int N) {
    __shared__ int sh[256];
    int t = threadIdx.x;
    int idx = blockIdx.x * 256 + t;
    int v = (idx < N) ? counts[idx] : 0;
    sh[t] = v;
    __syncthreads();
    for (int off = 1; off < 256; off <<= 1) {
        int add = (t >= off) ? sh[t - off] : 0;
        __syncthreads();
        sh[t] += add;
        __syncthreads();
    }
    if (idx < N) {
        int ex = bpre[blockIdx.x] + sh[t] - v;
        offs[idx] = ex;
        cursor[idx] = ex;
    }
}

// ---- scatter edge ids into dst-sorted order ----
__global__ void k_ids(const int* ei, int* cursor, int* sorted, int E, int N) {
    int e = blockIdx.x * 256 + threadIdx.x;
    if (e >= E) return;
    int d = clampi(ei[E + e], N);
    int pos = atomicAdd(&cursor[d], 1);
    sorted[pos] = e;
}

// ---- K4': per-dst-node segment softmax + weighted gather-aggregate ----
// One wave per node. No atomics. agg row written once, coalesced.
// agg = (sum_e ex * right[src]) / (s + eps); att = ex / (s + eps).
__global__ __launch_bounds__(256) void k_gather(
    const int* ei, const int* offs, const int* counts, const int* sorted,
    const float* right, float* att_slot, float* agg, int N)
{
    int w = threadIdx.x >> 6, lane = threadIdx.x & 63;
    for (int n = blockIdx.x * 4 + w; n < N; n += gridDim.x * 4) {
        int start = offs[n], deg = counts[n];
        // pass 1: segment max (lane-parallel + wave reduce)
        float m0 = -1e30f, m1 = -1e30f;
        for (int i = lane; i < deg; i += 64) {
            int e = sorted[start + i];
            m0 = fmaxf(m0, att_slot[e * 2]);
            m1 = fmaxf(m1, att_slot[e * 2 + 1]);
        }
        #pragma unroll
        for (int m = 32; m >= 1; m >>= 1) {
            m0 = fmaxf(m0, __shfl_xor(m0, m, 64));
            m1 = fmaxf(m1, __shfl_xor(m1, m, 64));
        }
        // pass 2: ex per edge (lane-parallel), sum-reduce, then
        // dim-parallel accumulation via shuffled broadcasts
        float s0 = 0.f, s1 = 0.f, acc0 = 0.f, acc1 = 0.f;
        for (int base = 0; base < deg; base += 64) {
            int cnt = min(deg - base, 64);
            float ex0 = 0.f, ex1 = 0.f; int src = 0;
            if (lane < cnt) {
                int e = sorted[start + base + lane];
                ex0 = __expf(att_slot[e * 2]     - m0);
                ex1 = __expf(att_slot[e * 2 + 1] - m1);
                src = clampi(ei[e], N);
            }
            float t0 = ex0, t1 = ex1;
            #pragma unroll
            for (int m = 32; m >= 1; m >>= 1) {
                t0 += __shfl_xor(t0, m, 64); t1 += __shfl_xor(t1, m, 64);
            }
            s0 += t0; s1 += t1;
            for (int i = 0; i < cnt; i++) {
                float w0 = __shfl(ex0, i, 64);
                float w1 = __shfl(ex1, i, 64);
                int   si = __shfl(src, i, 64);
                float v = right[(size_t)si * DD + lane];
                acc0 += w0 * v; acc1 += w1 * v;
            }
        }
        float inv0 = 1.f / (s0 + 1e-16f), inv1 = 1.f / (s1 + 1e-16f);
        // pass 3: write normalized att (lane-parallel; recompute exp from alpha)
        for (int i = lane; i < deg; i += 64) {
            int e = sorted[start + i];
            att_slot[e * 2]     = __expf(att_slot[e * 2]     - m0) * inv0;
            att_slot[e * 2 + 1] = __expf(att_slot[e * 2 + 1] - m1) * inv1;
        }
        agg[(size_t)n * HC + lane]      = acc0 * inv0;
        agg[(size_t)n * HC + 64 + lane] = acc1 * inv1;
    }
}

// ---- K5: fused dense chain (unchanged) ----
__global__ __launch_bounds__(256) void k_post(
    const float* agg, const float* left, const float* W_lin,
    const float* bias_conv, const float* W_lt, const float* b_lt,
    const float* W_fm, const float* b_fm,
    const float* W_pc, const float* b_pc,
    float* out_lu, int N)
{
    __shared__ ushort16 sWlin[DD * HC];    // 16 KB
    __shared__ ushort16 sWlt[HC * CC];     // 16 KB
    __shared__ ushort16 sWfm[CC * CC];     // 8 KB
    __shared__ ushort16 sWpc[HC * CC];     // 16 KB
    __shared__ float sBc[HC], sBlt[CC], sBfm[CC], sBpc[CC];
    __shared__ float t0[4][HC], t1[4][CC], t2[4][CC];
    for (int i = threadIdx.x; i < DD * HC; i += 256) {
        sWlin[i] = f2bf(W_lin[i]);
        sWlt[i]  = f2bf(W_lt[i]);
        sWpc[i]  = f2bf(W_pc[i]);
    }
    for (int i = threadIdx.x; i < CC * CC; i += 256)
        sWfm[i] = f2bf(W_fm[i]);
    if (threadIdx.x < HC) sBc[threadIdx.x] = bias_conv[threadIdx.x];
    if (threadIdx.x < CC) {
        sBlt[threadIdx.x] = b_lt[threadIdx.x];
        sBfm[threadIdx.x] = b_fm[threadIdx.x];
        sBpc[threadIdx.x] = b_pc[threadIdx.x];
    }
    __syncthreads();
    int r = threadIdx.x >> 6;              // one wave per row
    int j = threadIdx.x & 63;
    for (int base = blockIdx.x * 4; base < N; base += gridDim.x * 4) {
        int n = base + r;
        bool act = (n < N);
        if (act) {
            const float* arow = agg + (size_t)n * HC;
            float ua = sBc[j], ub = sBc[64 + j];
            #pragma unroll
            for (int d = 0; d < DD; d++) {
                ua += arow[d]      * bf2f(sWlin[d * HC + j]);
                ub += arow[64 + d] * bf2f(sWlin[d * HC + 64 + j]);
            }
            t0[r][j] = fmaxf(ua, 0.f); t0[r][64 + j] = fmaxf(ub, 0.f);
        }
        __syncthreads();
        if (act) {
            float acc = sBlt[j];
            #pragma unroll
            for (int k = 0; k < HC; k++) acc += t0[r][k] * bf2f(sWlt[k * CC + j]);
            t1[r][j] = fmaxf(acc, 0.f);
        }
        __syncthreads();
        if (act) {
            float acc = sBfm[j];
            #pragma unroll
            for (int k = 0; k < CC; k++) acc += t1[r][k] * bf2f(sWfm[k * CC + j]);
            t2[r][j] = acc;
        }
        __syncthreads();
        if (act) {
            float acc = sBpc[j];
            const float* lrow = left + (size_t)n * DD;
            #pragma unroll
            for (int k = 0; k < CC; k++) acc += lrow[k] * bf2f(sWpc[k * CC + j]);
            #pragma unroll
            for (int k = 0; k < CC; k++) acc += t2[r][k] * bf2f(sWpc[(64 + k) * CC + j]);
            out_lu[(size_t)n * CC + j] = acc;
        }
        __syncthreads();
    }
}

// ---- K6: edge_index -> float copy into output slot 1 ----
__global__ void k_copy_idx(const int* ei, float* out, int n) {
    for (int i = blockIdx.x * blockDim.x + threadIdx.x; i < n;
         i += gridDim.x * blockDim.x)
        out[i] = (float)ei[i];
}

extern "C" void kernel_launch(void* const* d_in, const int* in_sizes, int n_in,
                              void* d_out, int out_size, void* d_ws, size_t ws_size,
                              hipStream_t stream) {
    const float* left      = (const float*)d_in[0];
    const int*   ei        = (const int*)d_in[1];
    const float* efeat     = (const float*)d_in[2];
    const float* right     = (const float*)d_in[3];
    const float* W_lin     = (const float*)d_in[5];
    const float* att_src   = (const float*)d_in[6];
    const float* att_dst   = (const float*)d_in[7];
    const float* W_edge    = (const float*)d_in[8];
    const float* att_edge  = (const float*)d_in[9];
    const float* bias_conv = (const float*)d_in[10];
    const float* W_lt      = (const float*)d_in[11];
    const float* b_lt      = (const float*)d_in[12];
    const float* W_fm      = (const float*)d_in[13];
    const float* b_fm      = (const float*)d_in[14];
    const float* W_pc      = (const float*)d_in[15];
    const float* b_pc      = (const float*)d_in[16];

    const int N = in_sizes[0] / DD;     // 50000
    const int E = in_sizes[2] / DD;     // 800000
    const int NB = (N + 255) / 256;     // 196 scan blocks (must be <= 256)

    // ws layout (4B units):
    //   vfold 512 | a_src 2N | a_dst 2N | counts N | offs N | cursor N |
    //   bsum 256 | bpre 256 | sorted E | agg 128N            (~30.2 MB)
    float* ws     = (float*)d_ws;
    float* vfold  = ws;
    float* a_src  = ws + 512;
    float* a_dst  = a_src + 2 * (size_t)N;
    int*   counts = (int*)(a_dst + 2 * (size_t)N);
    int*   offs   = counts + N;
    int*   cursor = offs + N;
    int*   bsum   = cursor + N;
    int*   bpre   = bsum + 256;
    int*   sorted = bpre + 256;
    float* agg    = (float*)(sorted + E);
    (void)ws_size; (void)n_in; (void)out_size;

    float* out_lu   = (float*)d_out;                 // [N,64]
    float* out_ei   = out_lu + (size_t)N * CC;       // [2,E] as float
    float* att_slot = out_ei + (size_t)2 * E;        // [E,2]: alpha -> att

    hipMemsetAsync(counts, 0, (size_t)N * sizeof(int), stream);

    hipLaunchKernelGGL(k_fold, dim3(1), dim3(128), 0, stream,
                       W_lin, att_src, att_dst, W_edge, att_edge, vfold);
    hipLaunchKernelGGL(k_node_logits, dim3(1024), dim3(256), 0, stream,
                       right, left, vfold, a_src, a_dst, N);
    hipLaunchKernelGGL(k_hist, dim3((E + 255) / 256), dim3(256), 0, stream,
                       ei, counts, E, N);
    hipLaunchKernelGGL(k_scan1, dim3(NB), dim3(256), 0, stream,
                       counts, bsum, N);
    hipLaunchKernelGGL(k_scan2, dim3(1), dim3(256), 0, stream,
                       bsum, bpre, NB);
    hipLaunchKernelGGL(k_scan3, dim3(NB), dim3(256), 0, stream,
                       counts, bpre, offs, cursor, N);
    hipLaunchKernelGGL(k_ids, dim3((E + 255) / 256), dim3(256), 0, stream,
                       ei, cursor, sorted, E, N);
    hipLaunchKernelGGL(k_edge_alpha, dim3((E + 3) / 4), dim3(256), 0, stream,
                       efeat, ei, vfold, a_src, a_dst, att_slot, E, N);
    hipLaunchKernelGGL(k_gather, dim3((N + 3) / 4), dim3(256), 0, stream,
                       ei, offs, counts, sorted, right, att_slot, agg, N);
    hipLaunchKernelGGL(k_post, dim3(512), dim3(256), 0, stream,
                       agg, left, W_lin, bias_conv, W_lt, b_lt, W_fm, b_fm,
                       W_pc, b_pc, out_lu, N);
    hipLaunchKernelGGL(k_copy_idx, dim3(1024), dim3(256), 0, stream,
                       ei, out_ei, 2 * E);
}

// Round 2
// 684.541 us; speedup vs baseline: 3.1732x; 1.2816x over previous
//
#include <hip/hip_runtime.h>
#include <hip/hip_bf16.h>

typedef unsigned int uint32;
typedef unsigned short ushort16;

#define HH 2
#define CC 64
#define DD 64
#define HC 128

__device__ __forceinline__ float bf2f(ushort16 u) {
    union { float f; uint32 u; } x; x.u = ((uint32)u) << 16; return x.f;
}
__device__ __forceinline__ ushort16 f2bf(float f) {
    union { float f; uint32 u; } x; x.f = f;
    uint32 u = x.u;
    u += 0x7FFFu + ((u >> 16) & 1u);   // round-to-nearest-even
    return (ushort16)(u >> 16);
}
__device__ __forceinline__ int clampi(int v, int N) {
    return min(max(v, 0), N - 1);
}

// ---- K0: fold attention vectors into weight matrices ----
__global__ void k_fold(const float* W_lin, const float* att_src,
                       const float* att_dst, const float* W_edge,
                       const float* att_edge, float* vfold) {
    int t = threadIdx.x;            // 128 threads: t = h*64+d
    int h = t >> 6, d = t & 63;
    float vs = 0.f, vd = 0.f, ve = 0.f;
    for (int c = 0; c < CC; c++) {
        float wl = W_lin[d * HC + h * CC + c];
        vs += wl * att_src[h * CC + c];
        vd += wl * att_dst[h * CC + c];
        ve += W_edge[d * HC + h * CC + c] * att_edge[h * CC + c];
    }
    vfold[t] = vs; vfold[128 + t] = vd; vfold[256 + t] = ve;
}

// ---- K1: per-node logits, thread-per-node (no shuffles) ----
__global__ __launch_bounds__(256) void k_node_logits(
    const float* right, const float* left, const float* vfold,
    float* a_src, float* a_dst, int N)
{
    __shared__ float vs[HC], vd[HC];
    if (threadIdx.x < HC) {
        vs[threadIdx.x] = vfold[threadIdx.x];
        vd[threadIdx.x] = vfold[HC + threadIdx.x];
    }
    __syncthreads();
    int n = blockIdx.x * 256 + threadIdx.x;
    if (n >= N) return;
    const float4* rr = (const float4*)(right + (size_t)n * DD);
    const float4* lr = (const float4*)(left  + (size_t)n * DD);
    float p0 = 0.f, p1 = 0.f, q0 = 0.f, q1 = 0.f;
    #pragma unroll
    for (int i = 0; i < 16; i++) {
        float4 r4 = rr[i], l4 = lr[i];
        float4 s0 = *(const float4*)&vs[i * 4];
        float4 s1 = *(const float4*)&vs[64 + i * 4];
        float4 d0 = *(const float4*)&vd[i * 4];
        float4 d1 = *(const float4*)&vd[64 + i * 4];
        p0 += r4.x * s0.x + r4.y * s0.y + r4.z * s0.z + r4.w * s0.w;
        p1 += r4.x * s1.x + r4.y * s1.y + r4.z * s1.z + r4.w * s1.w;
        q0 += l4.x * d0.x + l4.y * d0.y + l4.z * d0.z + l4.w * d0.w;
        q1 += l4.x * d1.x + l4.y * d1.y + l4.z * d1.z + l4.w * d1.w;
    }
    *(float2*)(a_src + (size_t)n * 2) = make_float2(p0, p1);
    *(float2*)(a_dst + (size_t)n * 2) = make_float2(q0, q1);
}

// ---- K2: thread-per-edge alpha GEMV + leaky-relu + fused dst histogram ----
__global__ __launch_bounds__(256) void k_edge_alpha(
    const float* edge_feat, const int* ei, const float* vfold,
    const float* a_src, const float* a_dst,
    float* att_slot, int* counts, int E, int N)
{
    __shared__ float vE[HC];
    if (threadIdx.x < HC) vE[threadIdx.x] = vfold[256 + threadIdx.x];
    __syncthreads();
    int e = blockIdx.x * 256 + threadIdx.x;
    if (e >= E) return;
    const float4* row = (const float4*)(edge_feat + (size_t)e * DD);
    float p0 = 0.f, p1 = 0.f;
    #pragma unroll
    for (int i = 0; i < 16; i++) {
        float4 f = row[i];
        float4 w0 = *(const float4*)&vE[i * 4];
        float4 w1 = *(const float4*)&vE[64 + i * 4];
        p0 += f.x * w0.x + f.y * w0.y + f.z * w0.z + f.w * w0.w;
        p1 += f.x * w1.x + f.y * w1.y + f.z * w1.z + f.w * w1.w;
    }
    int s  = clampi(ei[e], N);
    int d2 = clampi(ei[E + e], N);
    float2 asr = *(const float2*)(a_src + (size_t)s * 2);
    float2 ads = *(const float2*)(a_dst + (size_t)d2 * 2);
    float al0 = asr.x + ads.x + p0;
    float al1 = asr.y + ads.y + p1;
    al0 = (al0 > 0.f) ? al0 : 0.2f * al0;
    al1 = (al1 > 0.f) ? al1 : 0.2f * al1;
    *(float2*)(att_slot + (size_t)e * 2) = make_float2(al0, al1);
    atomicAdd(&counts[d2], 1);
}

// ---- scan stage 1: per-block sums of counts ----
__global__ void k_scan1(const int* counts, int* bsum, int N) {
    int idx = blockIdx.x * 256 + threadIdx.x;
    int v = (idx < N) ? counts[idx] : 0;
    #pragma unroll
    for (int m = 32; m >= 1; m >>= 1) v += __shfl_xor(v, m, 64);
    __shared__ int wsum[4];
    if ((threadIdx.x & 63) == 0) wsum[threadIdx.x >> 6] = v;
    __syncthreads();
    if (threadIdx.x == 0) bsum[blockIdx.x] = wsum[0] + wsum[1] + wsum[2] + wsum[3];
}

// ---- scan stage 2: exclusive scan of block sums (NB <= 256) ----
__global__ void k_scan2(const int* bsum, int* bpre, int NB) {
    __shared__ int sh[256];
    int t = threadIdx.x;
    int v = (t < NB) ? bsum[t] : 0;
    sh[t] = v;
    __syncthreads();
    for (int off = 1; off < 256; off <<= 1) {
        int add = (t >= off) ? sh[t - off] : 0;
        __syncthreads();
        sh[t] += add;
        __syncthreads();
    }
    if (t < NB) bpre[t] = sh[t] - v;   // exclusive prefix
}

// ---- scan stage 3: per-element exclusive offsets; init cursor ----
__global__ void k_scan3(const int* counts, const int* bpre,
                        int* offs, int* cursor, int N) {
    __shared__ int sh[256];
    int t = threadIdx.x;
    int idx = blockIdx.x * 256 + t;
    int v = (idx < N) ? counts[idx] : 0;
    sh[t] = v;
    __syncthreads();
    for (int off = 1; off < 256; off <<= 1) {
        int add = (t >= off) ? sh[t - off] : 0;
        __syncthreads();
        sh[t] += add;
        __syncthreads();
    }
    if (idx < N) {
        int ex = bpre[blockIdx.x] + sh[t] - v;
        offs[idx] = ex;
        cursor[idx] = ex;
    }
}

// ---- scatter edge ids into dst-sorted order ----
__global__ void k_ids(const int* ei, int* cursor, int* sorted, int E, int N) {
    int e = blockIdx.x * 256 + threadIdx.x;
    if (e >= E) return;
    int d = clampi(ei[E + e], N);
    int pos = atomicAdd(&cursor[d], 1);
    sorted[pos] = e;
}

// ---- K4': per-dst-node segment softmax + weighted gather-aggregate ----
__global__ __launch_bounds__(256) void k_gather(
    const int* ei, const int* offs, const int* counts, const int* sorted,
    const float* right, float* att_slot, float* agg, int N)
{
    int w = threadIdx.x >> 6, lane = threadIdx.x & 63;
    for (int n = blockIdx.x * 4 + w; n < N; n += gridDim.x * 4) {
        int start = offs[n], deg = counts[n];
        // pass 1: segment max (lane-parallel + wave reduce)
        float m0 = -1e30f, m1 = -1e30f;
        for (int i = lane; i < deg; i += 64) {
            int e = sorted[start + i];
            m0 = fmaxf(m0, att_slot[e * 2]);
            m1 = fmaxf(m1, att_slot[e * 2 + 1]);
        }
        #pragma unroll
        for (int m = 32; m >= 1; m >>= 1) {
            m0 = fmaxf(m0, __shfl_xor(m0, m, 64));
            m1 = fmaxf(m1, __shfl_xor(m1, m, 64));
        }
        // pass 2: ex per edge (lane-parallel), sum-reduce, then
        // dim-parallel accumulation via shuffled broadcasts
        float s0 = 0.f, s1 = 0.f, acc0 = 0.f, acc1 = 0.f;
        for (int base = 0; base < deg; base += 64) {
            int cnt = min(deg - base, 64);
            float ex0 = 0.f, ex1 = 0.f; int src = 0;
            if (lane < cnt) {
                int e = sorted[start + base + lane];
                ex0 = __expf(att_slot[e * 2]     - m0);
                ex1 = __expf(att_slot[e * 2 + 1] - m1);
                src = clampi(ei[e], N);
            }
            float t0 = ex0, t1 = ex1;
            #pragma unroll
            for (int m = 32; m >= 1; m >>= 1) {
                t0 += __shfl_xor(t0, m, 64); t1 += __shfl_xor(t1, m, 64);
            }
            s0 += t0; s1 += t1;
            for (int i = 0; i < cnt; i++) {
                float w0 = __shfl(ex0, i, 64);
                float w1 = __shfl(ex1, i, 64);
                int   si = __shfl(src, i, 64);
                float v = right[(size_t)si * DD + lane];
                acc0 += w0 * v; acc1 += w1 * v;
            }
        }
        float inv0 = 1.f / (s0 + 1e-16f), inv1 = 1.f / (s1 + 1e-16f);
        // pass 3: write normalized att (lane-parallel; recompute exp from alpha)
        for (int i = lane; i < deg; i += 64) {
            int e = sorted[start + i];
            att_slot[e * 2]     = __expf(att_slot[e * 2]     - m0) * inv0;
            att_slot[e * 2 + 1] = __expf(att_slot[e * 2 + 1] - m1) * inv1;
        }
        agg[(size_t)n * HC + lane]      = acc0 * inv0;
        agg[(size_t)n * HC + 64 + lane] = acc1 * inv1;
    }
}

// ---- K5: fused dense chain ----
__global__ __launch_bounds__(256) void k_post(
    const float* agg, const float* left, const float* W_lin,
    const float* bias_conv, const float* W_lt, const float* b_lt,
    const float* W_fm, const float* b_fm,
    const float* W_pc, const float* b_pc,
    float* out_lu, int N)
{
    __shared__ ushort16 sWlin[DD * HC];    // 16 KB
    __shared__ ushort16 sWlt[HC * CC];     // 16 KB
    __shared__ ushort16 sWfm[CC * CC];     // 8 KB
    __shared__ ushort16 sWpc[HC * CC];     // 16 KB
    __shared__ float sBc[HC], sBlt[CC], sBfm[CC], sBpc[CC];
    __shared__ float t0[4][HC], t1[4][CC], t2[4][CC];
    for (int i = threadIdx.x; i < DD * HC; i += 256) {
        sWlin[i] = f2bf(W_lin[i]);
        sWlt[i]  = f2bf(W_lt[i]);
        sWpc[i]  = f2bf(W_pc[i]);
    }
    for (int i = threadIdx.x; i < CC * CC; i += 256)
        sWfm[i] = f2bf(W_fm[i]);
    if (threadIdx.x < HC) sBc[threadIdx.x] = bias_conv[threadIdx.x];
    if (threadIdx.x < CC) {
        sBlt[threadIdx.x] = b_lt[threadIdx.x];
        sBfm[threadIdx.x] = b_fm[threadIdx.x];
        sBpc[threadIdx.x] = b_pc[threadIdx.x];
    }
    __syncthreads();
    int r = threadIdx.x >> 6;              // one wave per row
    int j = threadIdx.x & 63;
    for (int base = blockIdx.x * 4; base < N; base += gridDim.x * 4) {
        int n = base + r;
        bool act = (n < N);
        if (act) {
            const float* arow = agg + (size_t)n * HC;
            float ua = sBc[j], ub = sBc[64 + j];
            #pragma unroll
            for (int d = 0; d < DD; d++) {
                ua += arow[d]      * bf2f(sWlin[d * HC + j]);
                ub += arow[64 + d] * bf2f(sWlin[d * HC + 64 + j]);
            }
            t0[r][j] = fmaxf(ua, 0.f); t0[r][64 + j] = fmaxf(ub, 0.f);
        }
        __syncthreads();
        if (act) {
            float acc = sBlt[j];
            #pragma unroll
            for (int k = 0; k < HC; k++) acc += t0[r][k] * bf2f(sWlt[k * CC + j]);
            t1[r][j] = fmaxf(acc, 0.f);
        }
        __syncthreads();
        if (act) {
            float acc = sBfm[j];
            #pragma unroll
            for (int k = 0; k < CC; k++) acc += t1[r][k] * bf2f(sWfm[k * CC + j]);
            t2[r][j] = acc;
        }
        __syncthreads();
        if (act) {
            float acc = sBpc[j];
            const float* lrow = left + (size_t)n * DD;
            #pragma unroll
            for (int k = 0; k < CC; k++) acc += lrow[k] * bf2f(sWpc[k * CC + j]);
            #pragma unroll
            for (int k = 0; k < CC; k++) acc += t2[r][k] * bf2f(sWpc[(64 + k) * CC + j]);
            out_lu[(size_t)n * CC + j] = acc;
        }
        __syncthreads();
    }
}

// ---- K6: edge_index -> float copy into output slot 1 ----
__global__ void k_copy_idx(const int* ei, float* out, int n) {
    for (int i = blockIdx.x * blockDim.x + threadIdx.x; i < n;
         i += gridDim.x * blockDim.x)
        out[i] = (float)ei[i];
}

extern "C" void kernel_launch(void* const* d_in, const int* in_sizes, int n_in,
                              void* d_out, int out_size, void* d_ws, size_t ws_size,
                              hipStream_t stream) {
    const float* left      = (const float*)d_in[0];
    const int*   ei        = (const int*)d_in[1];
    const float* efeat     = (const float*)d_in[2];
    const float* right     = (const float*)d_in[3];
    const float* W_lin     = (const float*)d_in[5];
    const float* att_src   = (const float*)d_in[6];
    const float* att_dst   = (const float*)d_in[7];
    const float* W_edge    = (const float*)d_in[8];
    const float* att_edge  = (const float*)d_in[9];
    const float* bias_conv = (const float*)d_in[10];
    const float* W_lt      = (const float*)d_in[11];
    const float* b_lt      = (const float*)d_in[12];
    const float* W_fm      = (const float*)d_in[13];
    const float* b_fm      = (const float*)d_in[14];
    const float* W_pc      = (const float*)d_in[15];
    const float* b_pc      = (const float*)d_in[16];

    const int N = in_sizes[0] / DD;     // 50000
    const int E = in_sizes[2] / DD;     // 800000
    const int NB = (N + 255) / 256;     // 196 scan blocks (must be <= 256)

    // ws layout (4B units):
    //   vfold 512 | a_src 2N | a_dst 2N | counts N | offs N | cursor N |
    //   bsum 256 | bpre 256 | sorted E | agg 128N            (~30.2 MB)
    float* ws     = (float*)d_ws;
    float* vfold  = ws;
    float* a_src  = ws + 512;
    float* a_dst  = a_src + 2 * (size_t)N;
    int*   counts = (int*)(a_dst + 2 * (size_t)N);
    int*   offs   = counts + N;
    int*   cursor = offs + N;
    int*   bsum   = cursor + N;
    int*   bpre   = bsum + 256;
    int*   sorted = bpre + 256;
    float* agg    = (float*)(sorted + E);
    (void)ws_size; (void)n_in; (void)out_size;

    float* out_lu   = (float*)d_out;                 // [N,64]
    float* out_ei   = out_lu + (size_t)N * CC;       // [2,E] as float
    float* att_slot = out_ei + (size_t)2 * E;        // [E,2]: alpha -> att

    hipMemsetAsync(counts, 0, (size_t)N * sizeof(int), stream);

    hipLaunchKernelGGL(k_fold, dim3(1), dim3(128), 0, stream,
                       W_lin, att_src, att_dst, W_edge, att_edge, vfold);
    hipLaunchKernelGGL(k_node_logits, dim3((N + 255) / 256), dim3(256), 0, stream,
                       right, left, vfold, a_src, a_dst, N);
    hipLaunchKernelGGL(k_edge_alpha, dim3((E + 255) / 256), dim3(256), 0, stream,
                       efeat, ei, vfold, a_src, a_dst, att_slot, counts, E, N);
    hipLaunchKernelGGL(k_scan1, dim3(NB), dim3(256), 0, stream,
                       counts, bsum, N);
    hipLaunchKernelGGL(k_scan2, dim3(1), dim3(256), 0, stream,
                       bsum, bpre, NB);
    hipLaunchKernelGGL(k_scan3, dim3(NB), dim3(256), 0, stream,
                       counts, bpre, offs, cursor, N);
    hipLaunchKernelGGL(k_ids, dim3((E + 255) / 256), dim3(256), 0, stream,
                       ei, cursor, sorted, E, N);
    hipLaunchKernelGGL(k_gather, dim3((N + 3) / 4), dim3(256), 0, stream,
                       ei, offs, counts, sorted, right, att_slot, agg, N);
    hipLaunchKernelGGL(k_post, dim3(512), dim3(256), 0, stream,
                       agg, left, W_lin, bias_conv, W_lt, b_lt, W_fm, b_fm,
                       W_pc, b_pc, out_lu, N);
    hipLaunchKernelGGL(k_copy_idx, dim3(1024), dim3(256), 0, stream,
                       ei, out_ei, 2 * E);
}

// Round 3
// 554.376 us; speedup vs baseline: 3.9182x; 1.2348x over previous
//
#include <hip/hip_runtime.h>
#include <hip/hip_bf16.h>

typedef unsigned int uint32;
typedef unsigned short ushort16;
typedef float f32x4 __attribute__((ext_vector_type(4)));
typedef short bf16x8 __attribute__((ext_vector_type(8)));

#define HH 2
#define CC 64
#define DD 64
#define HC 128

__device__ __forceinline__ float bf2f(ushort16 u) {
    union { float f; uint32 u; } x; x.u = ((uint32)u) << 16; return x.f;
}
__device__ __forceinline__ ushort16 f2bf(float f) {
    union { float f; uint32 u; } x; x.f = f;
    uint32 u = x.u;
    u += 0x7FFFu + ((u >> 16) & 1u);   // round-to-nearest-even
    return (ushort16)(u >> 16);
}
__device__ __forceinline__ int clampi(int v, int N) {
    return min(max(v, 0), N - 1);
}
// split 8 floats into hi(truncated bf16) + lo(bf16 of residual): ~fp32 accuracy
__device__ __forceinline__ void cvt_hilo8(const float* x, bf16x8& hi, bf16x8& lo) {
    #pragma unroll
    for (int i = 0; i < 8; i++) {
        union { float f; uint32 u; } a; a.f = x[i];
        uint32 uh = a.u & 0xFFFF0000u;
        hi[i] = (short)(uh >> 16);
        union { float f; uint32 u; } hf; hf.u = uh;
        lo[i] = (short)f2bf(a.f - hf.f);
    }
}

// ---- K0: fold attention vectors into weight matrices ----
__global__ void k_fold(const float* W_lin, const float* att_src,
                       const float* att_dst, const float* W_edge,
                       const float* att_edge, float* vfold) {
    int t = threadIdx.x;            // 128 threads: t = h*64+d
    int h = t >> 6, d = t & 63;
    float vs = 0.f, vd = 0.f, ve = 0.f;
    for (int c = 0; c < CC; c++) {
        float wl = W_lin[d * HC + h * CC + c];
        vs += wl * att_src[h * CC + c];
        vd += wl * att_dst[h * CC + c];
        ve += W_edge[d * HC + h * CC + c] * att_edge[h * CC + c];
    }
    vfold[t] = vs; vfold[128 + t] = vd; vfold[256 + t] = ve;
}

// ---- K1: per-node logits, thread-per-node ----
__global__ __launch_bounds__(256) void k_node_logits(
    const float* right, const float* left, const float* vfold,
    float* a_src, float* a_dst, int N)
{
    __shared__ float vs[HC], vd[HC];
    if (threadIdx.x < HC) {
        vs[threadIdx.x] = vfold[threadIdx.x];
        vd[threadIdx.x] = vfold[HC + threadIdx.x];
    }
    __syncthreads();
    int n = blockIdx.x * 256 + threadIdx.x;
    if (n >= N) return;
    const float4* rr = (const float4*)(right + (size_t)n * DD);
    const float4* lr = (const float4*)(left  + (size_t)n * DD);
    float p0 = 0.f, p1 = 0.f, q0 = 0.f, q1 = 0.f;
    #pragma unroll
    for (int i = 0; i < 16; i++) {
        float4 r4 = rr[i], l4 = lr[i];
        float4 s0 = *(const float4*)&vs[i * 4];
        float4 s1 = *(const float4*)&vs[64 + i * 4];
        float4 d0 = *(const float4*)&vd[i * 4];
        float4 d1 = *(const float4*)&vd[64 + i * 4];
        p0 += r4.x * s0.x + r4.y * s0.y + r4.z * s0.z + r4.w * s0.w;
        p1 += r4.x * s1.x + r4.y * s1.y + r4.z * s1.z + r4.w * s1.w;
        q0 += l4.x * d0.x + l4.y * d0.y + l4.z * d0.z + l4.w * d0.w;
        q1 += l4.x * d1.x + l4.y * d1.y + l4.z * d1.z + l4.w * d1.w;
    }
    *(float2*)(a_src + (size_t)n * 2) = make_float2(p0, p1);
    *(float2*)(a_dst + (size_t)n * 2) = make_float2(q0, q1);
}

// ---- K2: thread-per-edge alpha GEMV + leaky-relu + fused dst histogram ----
__global__ __launch_bounds__(256) void k_edge_alpha(
    const float* edge_feat, const int* ei, const float* vfold,
    const float* a_src, const float* a_dst,
    float* att_slot, int* counts, int E, int N)
{
    __shared__ float vE[HC];
    if (threadIdx.x < HC) vE[threadIdx.x] = vfold[256 + threadIdx.x];
    __syncthreads();
    int e = blockIdx.x * 256 + threadIdx.x;
    if (e >= E) return;
    const float4* row = (const float4*)(edge_feat + (size_t)e * DD);
    float p0 = 0.f, p1 = 0.f;
    #pragma unroll
    for (int i = 0; i < 16; i++) {
        float4 f = row[i];
        float4 w0 = *(const float4*)&vE[i * 4];
        float4 w1 = *(const float4*)&vE[64 + i * 4];
        p0 += f.x * w0.x + f.y * w0.y + f.z * w0.z + f.w * w0.w;
        p1 += f.x * w1.x + f.y * w1.y + f.z * w1.z + f.w * w1.w;
    }
    int s  = clampi(ei[e], N);
    int d2 = clampi(ei[E + e], N);
    float2 asr = *(const float2*)(a_src + (size_t)s * 2);
    float2 ads = *(const float2*)(a_dst + (size_t)d2 * 2);
    float al0 = asr.x + ads.x + p0;
    float al1 = asr.y + ads.y + p1;
    al0 = (al0 > 0.f) ? al0 : 0.2f * al0;
    al1 = (al1 > 0.f) ? al1 : 0.2f * al1;
    *(float2*)(att_slot + (size_t)e * 2) = make_float2(al0, al1);
    atomicAdd(&counts[d2], 1);
}

// ---- scan stage 1: per-block sums of counts ----
__global__ void k_scan1(const int* counts, int* bsum, int N) {
    int idx = blockIdx.x * 256 + threadIdx.x;
    int v = (idx < N) ? counts[idx] : 0;
    #pragma unroll
    for (int m = 32; m >= 1; m >>= 1) v += __shfl_xor(v, m, 64);
    __shared__ int wsum[4];
    if ((threadIdx.x & 63) == 0) wsum[threadIdx.x >> 6] = v;
    __syncthreads();
    if (threadIdx.x == 0) bsum[blockIdx.x] = wsum[0] + wsum[1] + wsum[2] + wsum[3];
}

// ---- scan stage 2: exclusive scan of block sums (NB <= 256) ----
__global__ void k_scan2(const int* bsum, int* bpre, int NB) {
    __shared__ int sh[256];
    int t = threadIdx.x;
    int v = (t < NB) ? bsum[t] : 0;
    sh[t] = v;
    __syncthreads();
    for (int off = 1; off < 256; off <<= 1) {
        int add = (t >= off) ? sh[t - off] : 0;
        __syncthreads();
        sh[t] += add;
        __syncthreads();
    }
    if (t < NB) bpre[t] = sh[t] - v;   // exclusive prefix
}

// ---- scan stage 3: per-element exclusive offsets; init cursor ----
__global__ void k_scan3(const int* counts, const int* bpre,
                        int* offs, int* cursor, int N) {
    __shared__ int sh[256];
    int t = threadIdx.x;
    int idx = blockIdx.x * 256 + t;
    int v = (idx < N) ? counts[idx] : 0;
    sh[t] = v;
    __syncthreads();
    for (int off = 1; off < 256; off <<= 1) {
        int add = (t >= off) ? sh[t - off] : 0;
        __syncthreads();
        sh[t] += add;
        __syncthreads();
    }
    if (idx < N) {
        int ex = bpre[blockIdx.x] + sh[t] - v;
        offs[idx] = ex;
        cursor[idx] = ex;
    }
}

// ---- scatter edge ids into dst-sorted order ----
__global__ void k_ids(const int* ei, int* cursor, int* sorted, int E, int N) {
    int e = blockIdx.x * 256 + threadIdx.x;
    if (e >= E) return;
    int d = clampi(ei[E + e], N);
    int pos = atomicAdd(&cursor[d], 1);
    sorted[pos] = e;
}

// ---- K4: per-dst-node segment softmax + weighted gather-aggregate ----
__global__ __launch_bounds__(256) void k_gather(
    const int* ei, const int* offs, const int* counts, const int* sorted,
    const float* right, float* att_slot, float* agg, int N)
{
    int w = threadIdx.x >> 6, lane = threadIdx.x & 63;
    for (int n = blockIdx.x * 4 + w; n < N; n += gridDim.x * 4) {
        int start = offs[n], deg = counts[n];
        float m0 = -1e30f, m1 = -1e30f;
        for (int i = lane; i < deg; i += 64) {
            int e = sorted[start + i];
            m0 = fmaxf(m0, att_slot[e * 2]);
            m1 = fmaxf(m1, att_slot[e * 2 + 1]);
        }
        #pragma unroll
        for (int m = 32; m >= 1; m >>= 1) {
            m0 = fmaxf(m0, __shfl_xor(m0, m, 64));
            m1 = fmaxf(m1, __shfl_xor(m1, m, 64));
        }
        float s0 = 0.f, s1 = 0.f, acc0 = 0.f, acc1 = 0.f;
        for (int base = 0; base < deg; base += 64) {
            int cnt = min(deg - base, 64);
            float ex0 = 0.f, ex1 = 0.f; int src = 0;
            if (lane < cnt) {
                int e = sorted[start + base + lane];
                ex0 = __expf(att_slot[e * 2]     - m0);
                ex1 = __expf(att_slot[e * 2 + 1] - m1);
                src = clampi(ei[e], N);
            }
            float t0 = ex0, t1 = ex1;
            #pragma unroll
            for (int m = 32; m >= 1; m >>= 1) {
                t0 += __shfl_xor(t0, m, 64); t1 += __shfl_xor(t1, m, 64);
            }
            s0 += t0; s1 += t1;
            for (int i = 0; i < cnt; i++) {
                float w0 = __shfl(ex0, i, 64);
                float w1 = __shfl(ex1, i, 64);
                int   si = __shfl(src, i, 64);
                float v = right[(size_t)si * DD + lane];
                acc0 += w0 * v; acc1 += w1 * v;
            }
        }
        float inv0 = 1.f / (s0 + 1e-16f), inv1 = 1.f / (s1 + 1e-16f);
        for (int i = lane; i < deg; i += 64) {
            int e = sorted[start + i];
            att_slot[e * 2]     = __expf(att_slot[e * 2]     - m0) * inv0;
            att_slot[e * 2 + 1] = __expf(att_slot[e * 2 + 1] - m1) * inv1;
        }
        agg[(size_t)n * HC + lane]      = acc0 * inv0;
        agg[(size_t)n * HC + 64 + lane] = acc1 * inv1;
    }
}

// ---- KP1 (MFMA): t0 = relu(agg @ Wlin_blockdiag + bc), IN PLACE over agg ----
// mfma_f32_16x16x32_bf16; A: row=lane&15, k=8*(lane>>4)+i; B: col=lane&15, same k;
// D: col=lane&15, row=4*(lane>>4)+reg. Activations hi/lo-split for fp32-like accuracy.
__global__ __launch_bounds__(256) void k_lin_mfma(
    const float* __restrict__ W_lin, const float* __restrict__ bc,
    float* agg, int N)
{
    __shared__ __align__(16) ushort16 sW[16][512];  // [h*8+kt*4+nt][lane*8+i]  16KB
    __shared__ float sB[HC];
    for (int t = threadIdx.x; t < 16 * 64; t += 256) {
        int lane = t & 63, f = t >> 6;
        int nt = f & 3, kt = (f >> 2) & 1, h = f >> 3;
        int n = h * CC + nt * 16 + (lane & 15);
        int k0 = kt * 32 + (lane >> 4) * 8;
        #pragma unroll
        for (int i = 0; i < 8; i++)
            sW[f][lane * 8 + i] = f2bf(W_lin[(size_t)(k0 + i) * HC + n]);
    }
    if (threadIdx.x < HC) sB[threadIdx.x] = bc[threadIdx.x];
    __syncthreads();
    int w = threadIdx.x >> 6, lane = threadIdx.x & 63;
    int lhi = lane >> 4, llo = lane & 15;
    int tiles = (N + 63) >> 6;
    for (int tile = blockIdx.x; tile < tiles; tile += gridDim.x) {
        int nb = tile * 64 + w * 16;
        int arow = min(nb + llo, N - 1);
        const float* ap = agg + (size_t)arow * HC;
        bf16x8 Ah[2][2], Al[2][2];
        #pragma unroll
        for (int h = 0; h < 2; h++)
            #pragma unroll
            for (int kt = 0; kt < 2; kt++) {
                float x8[8];
                *(f32x4*)&x8[0] = *(const f32x4*)(ap + h * 64 + kt * 32 + lhi * 8);
                *(f32x4*)&x8[4] = *(const f32x4*)(ap + h * 64 + kt * 32 + lhi * 8 + 4);
                cvt_hilo8(x8, Ah[h][kt], Al[h][kt]);
            }
        f32x4 acc[2][4];
        #pragma unroll
        for (int h = 0; h < 2; h++)
            #pragma unroll
            for (int nt = 0; nt < 4; nt++) {
                float b = sB[h * 64 + nt * 16 + llo];
                acc[h][nt][0] = b; acc[h][nt][1] = b;
                acc[h][nt][2] = b; acc[h][nt][3] = b;
            }
        #pragma unroll
        for (int h = 0; h < 2; h++)
            #pragma unroll
            for (int kt = 0; kt < 2; kt++)
                #pragma unroll
                for (int nt = 0; nt < 4; nt++) {
                    bf16x8 b = *(const bf16x8*)&sW[h * 8 + kt * 4 + nt][lane * 8];
                    acc[h][nt] = __builtin_amdgcn_mfma_f32_16x16x32_bf16(Al[h][kt], b, acc[h][nt], 0, 0, 0);
                    acc[h][nt] = __builtin_amdgcn_mfma_f32_16x16x32_bf16(Ah[h][kt], b, acc[h][nt], 0, 0, 0);
                }
        #pragma unroll
        for (int h = 0; h < 2; h++)
            #pragma unroll
            for (int nt = 0; nt < 4; nt++)
                #pragma unroll
                for (int j = 0; j < 4; j++) {
                    int node = nb + 4 * lhi + j;
                    if (node < N)
                        agg[(size_t)node * HC + h * 64 + nt * 16 + llo] =
                            fmaxf(acc[h][nt][j], 0.f);
                }
    }
}

// ---- KP2 (MFMA): out = [left, (relu(t0@Wlt+blt))@Wfm+bfm] @ Wpc + bpc ----
__global__ __launch_bounds__(256) void k_tail_mfma(
    const float* __restrict__ t0, const float* __restrict__ left,
    const float* __restrict__ W_lt, const float* __restrict__ b_lt,
    const float* __restrict__ W_fm, const float* __restrict__ b_fm,
    const float* __restrict__ W_pc, const float* __restrict__ b_pc,
    float* __restrict__ out, int N)
{
    __shared__ __align__(16) ushort16 sWlt[16][512];  // 16KB
    __shared__ __align__(16) ushort16 sWfm[8][512];   // 8KB
    __shared__ __align__(16) ushort16 sWpT[8][512];   // 8KB
    __shared__ __align__(16) ushort16 sWpB[8][512];   // 8KB
    __shared__ __align__(16) float sX[4][1024];       // 16KB, per-wave swizzled
    __shared__ float sblt[CC], sbfm[CC], sbpc[CC];
    for (int t = threadIdx.x; t < 16 * 64; t += 256) {
        int lane = t & 63, f = t >> 6, nt = f & 3, kt = f >> 2;
        int n = nt * 16 + (lane & 15), k0 = kt * 32 + (lane >> 4) * 8;
        #pragma unroll
        for (int i = 0; i < 8; i++)
            sWlt[f][lane * 8 + i] = f2bf(W_lt[(k0 + i) * CC + n]);
    }
    for (int t = threadIdx.x; t < 8 * 64; t += 256) {
        int lane = t & 63, f = t >> 6, nt = f & 3, kt = f >> 2;
        int n = nt * 16 + (lane & 15), k0 = kt * 32 + (lane >> 4) * 8;
        #pragma unroll
        for (int i = 0; i < 8; i++) {
            sWfm[f][lane * 8 + i] = f2bf(W_fm[(k0 + i) * CC + n]);
            sWpT[f][lane * 8 + i] = f2bf(W_pc[(k0 + i) * CC + n]);
            sWpB[f][lane * 8 + i] = f2bf(W_pc[(64 + k0 + i) * CC + n]);
        }
    }
    if (threadIdx.x < CC) {
        sblt[threadIdx.x] = b_lt[threadIdx.x];
        sbfm[threadIdx.x] = b_fm[threadIdx.x];
        sbpc[threadIdx.x] = b_pc[threadIdx.x];
    }
    __syncthreads();
    int w = threadIdx.x >> 6, lane = threadIdx.x & 63;
    int lhi = lane >> 4, llo = lane & 15;
    float* xw = &sX[w][0];
    int swz = (llo & 7) << 2;          // read-side swizzle (row = llo)
    int tiles = (N + 63) >> 6;
    for (int tile = blockIdx.x; tile < tiles; tile += gridDim.x) {
        int nb = tile * 64 + w * 16;
        int arow = min(nb + llo, N - 1);
        // ---- layer2: X1 = relu(t0 @ Wlt + blt)
        f32x4 acc2[4];
        #pragma unroll
        for (int nt = 0; nt < 4; nt++) {
            float b = sblt[nt * 16 + llo];
            acc2[nt][0] = b; acc2[nt][1] = b; acc2[nt][2] = b; acc2[nt][3] = b;
        }
        const float* tp = t0 + (size_t)arow * HC;
        #pragma unroll
        for (int kt = 0; kt < 4; kt++) {
            float x8[8];
            *(f32x4*)&x8[0] = *(const f32x4*)(tp + kt * 32 + lhi * 8);
            *(f32x4*)&x8[4] = *(const f32x4*)(tp + kt * 32 + lhi * 8 + 4);
            bf16x8 ah, al; cvt_hilo8(x8, ah, al);
            #pragma unroll
            for (int nt = 0; nt < 4; nt++) {
                bf16x8 b = *(const bf16x8*)&sWlt[kt * 4 + nt][lane * 8];
                acc2[nt] = __builtin_amdgcn_mfma_f32_16x16x32_bf16(al, b, acc2[nt], 0, 0, 0);
                acc2[nt] = __builtin_amdgcn_mfma_f32_16x16x32_bf16(ah, b, acc2[nt], 0, 0, 0);
            }
        }
        #pragma unroll
        for (int nt = 0; nt < 4; nt++)
            #pragma unroll
            for (int j = 0; j < 4; j++) {
                int row = 4 * lhi + j, col = nt * 16 + llo;
                xw[row * 64 + (col ^ ((row & 7) << 2))] = fmaxf(acc2[nt][j], 0.f);
            }
        // ---- layer3: X2 = X1 @ Wfm + bfm (no relu)
        f32x4 acc3[4];
        #pragma unroll
        for (int nt = 0; nt < 4; nt++) {
            float b = sbfm[nt * 16 + llo];
            acc3[nt][0] = b; acc3[nt][1] = b; acc3[nt][2] = b; acc3[nt][3] = b;
        }
        #pragma unroll
        for (int kt = 0; kt < 2; kt++) {
            int k0 = kt * 32 + lhi * 8;
            float x8[8];
            *(f32x4*)&x8[0] = *(const f32x4*)&xw[llo * 64 + ((k0    ) ^ swz)];
            *(f32x4*)&x8[4] = *(const f32x4*)&xw[llo * 64 + ((k0 + 4) ^ swz)];
            bf16x8 ah, al; cvt_hilo8(x8, ah, al);
            #pragma unroll
            for (int nt = 0; nt < 4; nt++) {
                bf16x8 b = *(const bf16x8*)&sWfm[kt * 4 + nt][lane * 8];
                acc3[nt] = __builtin_amdgcn_mfma_f32_16x16x32_bf16(al, b, acc3[nt], 0, 0, 0);
                acc3[nt] = __builtin_amdgcn_mfma_f32_16x16x32_bf16(ah, b, acc3[nt], 0, 0, 0);
            }
        }
        #pragma unroll
        for (int nt = 0; nt < 4; nt++)
            #pragma unroll
            for (int j = 0; j < 4; j++) {
                int row = 4 * lhi + j, col = nt * 16 + llo;
                xw[row * 64 + (col ^ ((row & 7) << 2))] = acc3[nt][j];
            }
        // ---- layer4: out = left @ WpcT + X2 @ WpcB + bpc
        f32x4 acc4[4];
        #pragma unroll
        for (int nt = 0; nt < 4; nt++) {
            float b = sbpc[nt * 16 + llo];
            acc4[nt][0] = b; acc4[nt][1] = b; acc4[nt][2] = b; acc4[nt][3] = b;
        }
        const float* lp = left + (size_t)arow * DD;
        #pragma unroll
        for (int kt = 0; kt < 2; kt++) {
            float x8[8];
            *(f32x4*)&x8[0] = *(const f32x4*)(lp + kt * 32 + lhi * 8);
            *(f32x4*)&x8[4] = *(const f32x4*)(lp + kt * 32 + lhi * 8 + 4);
            bf16x8 ah, al; cvt_hilo8(x8, ah, al);
            #pragma unroll
            for (int nt = 0; nt < 4; nt++) {
                bf16x8 b = *(const bf16x8*)&sWpT[kt * 4 + nt][lane * 8];
                acc4[nt] = __builtin_amdgcn_mfma_f32_16x16x32_bf16(al, b, acc4[nt], 0, 0, 0);
                acc4[nt] = __builtin_amdgcn_mfma_f32_16x16x32_bf16(ah, b, acc4[nt], 0, 0, 0);
            }
        }
        #pragma unroll
        for (int kt = 0; kt < 2; kt++) {
            int k0 = kt * 32 + lhi * 8;
            float x8[8];
            *(f32x4*)&x8[0] = *(const f32x4*)&xw[llo * 64 + ((k0    ) ^ swz)];
            *(f32x4*)&x8[4] = *(const f32x4*)&xw[llo * 64 + ((k0 + 4) ^ swz)];
            bf16x8 ah, al; cvt_hilo8(x8, ah, al);
            #pragma unroll
            for (int nt = 0; nt < 4; nt++) {
                bf16x8 b = *(const bf16x8*)&sWpB[kt * 4 + nt][lane * 8];
                acc4[nt] = __builtin_amdgcn_mfma_f32_16x16x32_bf16(al, b, acc4[nt], 0, 0, 0);
                acc4[nt] = __builtin_amdgcn_mfma_f32_16x16x32_bf16(ah, b, acc4[nt], 0, 0, 0);
            }
        }
        #pragma unroll
        for (int nt = 0; nt < 4; nt++)
            #pragma unroll
            for (int j = 0; j < 4; j++) {
                int node = nb + 4 * lhi + j;
                if (node < N)
                    out[(size_t)node * CC + nt * 16 + llo] = acc4[nt][j];
            }
    }
}

// ---- K6: edge_index -> float copy into output slot 1 ----
__global__ void k_copy_idx(const int* ei, float* out, int n) {
    for (int i = blockIdx.x * blockDim.x + threadIdx.x; i < n;
         i += gridDim.x * blockDim.x)
        out[i] = (float)ei[i];
}

extern "C" void kernel_launch(void* const* d_in, const int* in_sizes, int n_in,
                              void* d_out, int out_size, void* d_ws, size_t ws_size,
                              hipStream_t stream) {
    const float* left      = (const float*)d_in[0];
    const int*   ei        = (const int*)d_in[1];
    const float* efeat     = (const float*)d_in[2];
    const float* right     = (const float*)d_in[3];
    const float* W_lin     = (const float*)d_in[5];
    const float* att_src   = (const float*)d_in[6];
    const float* att_dst   = (const float*)d_in[7];
    const float* W_edge    = (const float*)d_in[8];
    const float* att_edge  = (const float*)d_in[9];
    const float* bias_conv = (const float*)d_in[10];
    const float* W_lt      = (const float*)d_in[11];
    const float* b_lt      = (const float*)d_in[12];
    const float* W_fm      = (const float*)d_in[13];
    const float* b_fm      = (const float*)d_in[14];
    const float* W_pc      = (const float*)d_in[15];
    const float* b_pc      = (const float*)d_in[16];

    const int N = in_sizes[0] / DD;     // 50000
    const int E = in_sizes[2] / DD;     // 800000
    const int NB = (N + 255) / 256;     // 196 scan blocks (must be <= 256)

    // ws layout (4B units):
    //   vfold 512 | a_src 2N | a_dst 2N | counts N | offs N | cursor N |
    //   bsum 256 | bpre 256 | sorted E | agg 128N            (~30.2 MB)
    float* ws     = (float*)d_ws;
    float* vfold  = ws;
    float* a_src  = ws + 512;
    float* a_dst  = a_src + 2 * (size_t)N;
    int*   counts = (int*)(a_dst + 2 * (size_t)N);
    int*   offs   = counts + N;
    int*   cursor = offs + N;
    int*   bsum   = cursor + N;
    int*   bpre   = bsum + 256;
    int*   sorted = bpre + 256;
    float* agg    = (float*)(sorted + E);
    (void)ws_size; (void)n_in; (void)out_size;

    float* out_lu   = (float*)d_out;                 // [N,64]
    float* out_ei   = out_lu + (size_t)N * CC;       // [2,E] as float
    float* att_slot = out_ei + (size_t)2 * E;        // [E,2]: alpha -> att

    hipMemsetAsync(counts, 0, (size_t)N * sizeof(int), stream);

    hipLaunchKernelGGL(k_fold, dim3(1), dim3(128), 0, stream,
                       W_lin, att_src, att_dst, W_edge, att_edge, vfold);
    hipLaunchKernelGGL(k_node_logits, dim3((N + 255) / 256), dim3(256), 0, stream,
                       right, left, vfold, a_src, a_dst, N);
    hipLaunchKernelGGL(k_edge_alpha, dim3((E + 255) / 256), dim3(256), 0, stream,
                       efeat, ei, vfold, a_src, a_dst, att_slot, counts, E, N);
    hipLaunchKernelGGL(k_scan1, dim3(NB), dim3(256), 0, stream,
                       counts, bsum, N);
    hipLaunchKernelGGL(k_scan2, dim3(1), dim3(256), 0, stream,
                       bsum, bpre, NB);
    hipLaunchKernelGGL(k_scan3, dim3(NB), dim3(256), 0, stream,
                       counts, bpre, offs, cursor, N);
    hipLaunchKernelGGL(k_ids, dim3((E + 255) / 256), dim3(256), 0, stream,
                       ei, cursor, sorted, E, N);
    hipLaunchKernelGGL(k_gather, dim3((N + 3) / 4), dim3(256), 0, stream,
                       ei, offs, counts, sorted, right, att_slot, agg, N);
    hipLaunchKernelGGL(k_lin_mfma, dim3(512), dim3(256), 0, stream,
                       W_lin, bias_conv, agg, N);
    hipLaunchKernelGGL(k_tail_mfma, dim3(512), dim3(256), 0, stream,
                       agg, left, W_lt, b_lt, W_fm, b_fm, W_pc, b_pc, out_lu, N);
    hipLaunchKernelGGL(k_copy_idx, dim3(1024), dim3(256), 0, stream,
                       ei, out_ei, 2 * E);
}

// Round 4
// 541.125 us; speedup vs baseline: 4.0141x; 1.0245x over previous
//
#include <hip/hip_runtime.h>
#include <hip/hip_bf16.h>

typedef unsigned int uint32;
typedef unsigned short ushort16;
typedef float f32x4 __attribute__((ext_vector_type(4)));
typedef short bf16x8 __attribute__((ext_vector_type(8)));

#define HH 2
#define CC 64
#define DD 64
#define HC 128

__device__ __forceinline__ float bf2f(ushort16 u) {
    union { float f; uint32 u; } x; x.u = ((uint32)u) << 16; return x.f;
}
__device__ __forceinline__ ushort16 f2bf(float f) {
    union { float f; uint32 u; } x; x.f = f;
    uint32 u = x.u;
    u += 0x7FFFu + ((u >> 16) & 1u);   // round-to-nearest-even
    return (ushort16)(u >> 16);
}
__device__ __forceinline__ int clampi(int v, int N) {
    return min(max(v, 0), N - 1);
}
// split 8 floats into hi(truncated bf16) + lo(bf16 of residual): ~fp32 accuracy
__device__ __forceinline__ void cvt_hilo8(const float* x, bf16x8& hi, bf16x8& lo) {
    #pragma unroll
    for (int i = 0; i < 8; i++) {
        union { float f; uint32 u; } a; a.f = x[i];
        uint32 uh = a.u & 0xFFFF0000u;
        hi[i] = (short)(uh >> 16);
        union { float f; uint32 u; } hf; hf.u = uh;
        lo[i] = (short)f2bf(a.f - hf.f);
    }
}

// ---- K0: fold attention vectors into weight matrices ----
__global__ void k_fold(const float* W_lin, const float* att_src,
                       const float* att_dst, const float* W_edge,
                       const float* att_edge, float* vfold) {
    int t = threadIdx.x;            // 128 threads: t = h*64+d
    int h = t >> 6, d = t & 63;
    float vs = 0.f, vd = 0.f, ve = 0.f;
    for (int c = 0; c < CC; c++) {
        float wl = W_lin[d * HC + h * CC + c];
        vs += wl * att_src[h * CC + c];
        vd += wl * att_dst[h * CC + c];
        ve += W_edge[d * HC + h * CC + c] * att_edge[h * CC + c];
    }
    vfold[t] = vs; vfold[128 + t] = vd; vfold[256 + t] = ve;
}

// ---- K1: per-node logits, thread-per-node ----
__global__ __launch_bounds__(256) void k_node_logits(
    const float* right, const float* left, const float* vfold,
    float* a_src, float* a_dst, int N)
{
    __shared__ float vs[HC], vd[HC];
    if (threadIdx.x < HC) {
        vs[threadIdx.x] = vfold[threadIdx.x];
        vd[threadIdx.x] = vfold[HC + threadIdx.x];
    }
    __syncthreads();
    int n = blockIdx.x * 256 + threadIdx.x;
    if (n >= N) return;
    const float4* rr = (const float4*)(right + (size_t)n * DD);
    const float4* lr = (const float4*)(left  + (size_t)n * DD);
    float p0 = 0.f, p1 = 0.f, q0 = 0.f, q1 = 0.f;
    #pragma unroll
    for (int i = 0; i < 16; i++) {
        float4 r4 = rr[i], l4 = lr[i];
        float4 s0 = *(const float4*)&vs[i * 4];
        float4 s1 = *(const float4*)&vs[64 + i * 4];
        float4 d0 = *(const float4*)&vd[i * 4];
        float4 d1 = *(const float4*)&vd[64 + i * 4];
        p0 += r4.x * s0.x + r4.y * s0.y + r4.z * s0.z + r4.w * s0.w;
        p1 += r4.x * s1.x + r4.y * s1.y + r4.z * s1.z + r4.w * s1.w;
        q0 += l4.x * d0.x + l4.y * d0.y + l4.z * d0.z + l4.w * d0.w;
        q1 += l4.x * d1.x + l4.y * d1.y + l4.z * d1.z + l4.w * d1.w;
    }
    *(float2*)(a_src + (size_t)n * 2) = make_float2(p0, p1);
    *(float2*)(a_dst + (size_t)n * 2) = make_float2(q0, q1);
}

// ---- K2: thread-per-edge alpha GEMV + leaky-relu + fused dst histogram ----
__global__ __launch_bounds__(256) void k_edge_alpha(
    const float* edge_feat, const int* ei, const float* vfold,
    const float* a_src, const float* a_dst,
    float* att_slot, int* counts, int E, int N)
{
    __shared__ float vE[HC];
    if (threadIdx.x < HC) vE[threadIdx.x] = vfold[256 + threadIdx.x];
    __syncthreads();
    int e = blockIdx.x * 256 + threadIdx.x;
    if (e >= E) return;
    const float4* row = (const float4*)(edge_feat + (size_t)e * DD);
    float p0 = 0.f, p1 = 0.f;
    #pragma unroll
    for (int i = 0; i < 16; i++) {
        float4 f = row[i];
        float4 w0 = *(const float4*)&vE[i * 4];
        float4 w1 = *(const float4*)&vE[64 + i * 4];
        p0 += f.x * w0.x + f.y * w0.y + f.z * w0.z + f.w * w0.w;
        p1 += f.x * w1.x + f.y * w1.y + f.z * w1.z + f.w * w1.w;
    }
    int s  = clampi(ei[e], N);
    int d2 = clampi(ei[E + e], N);
    float2 asr = *(const float2*)(a_src + (size_t)s * 2);
    float2 ads = *(const float2*)(a_dst + (size_t)d2 * 2);
    float al0 = asr.x + ads.x + p0;
    float al1 = asr.y + ads.y + p1;
    al0 = (al0 > 0.f) ? al0 : 0.2f * al0;
    al1 = (al1 > 0.f) ? al1 : 0.2f * al1;
    *(float2*)(att_slot + (size_t)e * 2) = make_float2(al0, al1);
    atomicAdd(&counts[d2], 1);
}

// ---- scan stage 1: per-block sums of counts ----
__global__ void k_scan1(const int* counts, int* bsum, int N) {
    int idx = blockIdx.x * 256 + threadIdx.x;
    int v = (idx < N) ? counts[idx] : 0;
    #pragma unroll
    for (int m = 32; m >= 1; m >>= 1) v += __shfl_xor(v, m, 64);
    __shared__ int wsum[4];
    if ((threadIdx.x & 63) == 0) wsum[threadIdx.x >> 6] = v;
    __syncthreads();
    if (threadIdx.x == 0) bsum[blockIdx.x] = wsum[0] + wsum[1] + wsum[2] + wsum[3];
}

// ---- scan stage 2: exclusive scan of block sums (NB <= 256) ----
__global__ void k_scan2(const int* bsum, int* bpre, int NB) {
    __shared__ int sh[256];
    int t = threadIdx.x;
    int v = (t < NB) ? bsum[t] : 0;
    sh[t] = v;
    __syncthreads();
    for (int off = 1; off < 256; off <<= 1) {
        int add = (t >= off) ? sh[t - off] : 0;
        __syncthreads();
        sh[t] += add;
        __syncthreads();
    }
    if (t < NB) bpre[t] = sh[t] - v;   // exclusive prefix
}

// ---- scan stage 3: per-element exclusive offsets; init cursor ----
__global__ void k_scan3(const int* counts, const int* bpre,
                        int* offs, int* cursor, int N) {
    __shared__ int sh[256];
    int t = threadIdx.x;
    int idx = blockIdx.x * 256 + t;
    int v = (idx < N) ? counts[idx] : 0;
    sh[t] = v;
    __syncthreads();
    for (int off = 1; off < 256; off <<= 1) {
        int add = (t >= off) ? sh[t - off] : 0;
        __syncthreads();
        sh[t] += add;
        __syncthreads();
    }
    if (idx < N) {
        int ex = bpre[blockIdx.x] + sh[t] - v;
        offs[idx] = ex;
        cursor[idx] = ex;
    }
}

// ---- scatter edge ids into dst-sorted order ----
__global__ void k_ids(const int* ei, int* cursor, int* sorted, int E, int N) {
    int e = blockIdx.x * 256 + threadIdx.x;
    if (e >= E) return;
    int d = clampi(ei[E + e], N);
    int pos = atomicAdd(&cursor[d], 1);
    sorted[pos] = e;
}

// ---- K4: per-dst-node segment softmax + weighted gather-aggregate ----
// Wave per node; 4 groups of 16 lanes each own one edge per iteration.
// Each lane loads float4 of the src row (16 lanes x 16B = 64 dims).
// No per-edge shuffles; one {16,32}-mask butterfly per node at the end.
__global__ __launch_bounds__(256) void k_gather(
    const int* ei, const int* offs, const int* counts, const int* sorted,
    const float* right, float* att_slot, float* agg, int N)
{
    int w = threadIdx.x >> 6, lane = threadIdx.x & 63;
    int g = lane >> 4, sub = lane & 15;
    for (int n = blockIdx.x * 4 + w; n < N; n += gridDim.x * 4) {
        int start = offs[n], deg = counts[n];
        // pass 1: segment max (lane-parallel + wave reduce)
        float m0 = -1e30f, m1 = -1e30f;
        for (int i = lane; i < deg; i += 64) {
            int e = sorted[start + i];
            float2 a = *(const float2*)(att_slot + (size_t)e * 2);
            m0 = fmaxf(m0, a.x);
            m1 = fmaxf(m1, a.y);
        }
        #pragma unroll
        for (int m = 32; m >= 1; m >>= 1) {
            m0 = fmaxf(m0, __shfl_xor(m0, m, 64));
            m1 = fmaxf(m1, __shfl_xor(m1, m, 64));
        }
        // pass 2: 4 edges/iteration; group g owns edge base+g.
        // Edge meta reads are same-address within a group (HW broadcast);
        // ex computed redundantly per lane (cheap), 4 row-gathers in flight.
        float s0 = 0.f, s1 = 0.f;
        f32x4 acc0 = {0.f, 0.f, 0.f, 0.f}, acc1 = {0.f, 0.f, 0.f, 0.f};
        for (int base = 0; base < deg; base += 4) {
            int i = base + g;
            if (i < deg) {
                int e = sorted[start + i];
                float2 a = *(const float2*)(att_slot + (size_t)e * 2);
                float ex0 = __expf(a.x - m0);
                float ex1 = __expf(a.y - m1);
                int si = clampi(ei[e], N);
                f32x4 v = *(const f32x4*)(right + (size_t)si * DD + sub * 4);
                acc0 += ex0 * v;
                acc1 += ex1 * v;
                s0 += ex0; s1 += ex1;
            }
        }
        // cross-group butterfly (groups' 16 lanes hold identical s-partials)
        s0 += __shfl_xor(s0, 16, 64); s0 += __shfl_xor(s0, 32, 64);
        s1 += __shfl_xor(s1, 16, 64); s1 += __shfl_xor(s1, 32, 64);
        #pragma unroll
        for (int j = 0; j < 4; j++) {
            acc0[j] += __shfl_xor(acc0[j], 16, 64);
            acc0[j] += __shfl_xor(acc0[j], 32, 64);
            acc1[j] += __shfl_xor(acc1[j], 16, 64);
            acc1[j] += __shfl_xor(acc1[j], 32, 64);
        }
        float inv0 = 1.f / (s0 + 1e-16f), inv1 = 1.f / (s1 + 1e-16f);
        // pass 3: write normalized att (lane-parallel)
        for (int i = lane; i < deg; i += 64) {
            int e = sorted[start + i];
            float2 a = *(const float2*)(att_slot + (size_t)e * 2);
            a.x = __expf(a.x - m0) * inv0;
            a.y = __expf(a.y - m1) * inv1;
            *(float2*)(att_slot + (size_t)e * 2) = a;
        }
        // coalesced float4 row writes: group 0 -> head 0, group 1 -> head 1
        if (g == 0) {
            f32x4 o = acc0 * inv0;
            *(f32x4*)(agg + (size_t)n * HC + sub * 4) = o;
        } else if (g == 1) {
            f32x4 o = acc1 * inv1;
            *(f32x4*)(agg + (size_t)n * HC + 64 + sub * 4) = o;
        }
    }
}

// ---- KP1 (MFMA): t0 = relu(agg @ Wlin_blockdiag + bc), IN PLACE over agg ----
// mfma_f32_16x16x32_bf16; A: row=lane&15, k=8*(lane>>4)+i; B: col=lane&15, same k;
// D: col=lane&15, row=4*(lane>>4)+reg. Activations hi/lo-split for fp32-like accuracy.
__global__ __launch_bounds__(256) void k_lin_mfma(
    const float* __restrict__ W_lin, const float* __restrict__ bc,
    float* agg, int N)
{
    __shared__ __align__(16) ushort16 sW[16][512];  // [h*8+kt*4+nt][lane*8+i]  16KB
    __shared__ float sB[HC];
    for (int t = threadIdx.x; t < 16 * 64; t += 256) {
        int lane = t & 63, f = t >> 6;
        int nt = f & 3, kt = (f >> 2) & 1, h = f >> 3;
        int n = h * CC + nt * 16 + (lane & 15);
        int k0 = kt * 32 + (lane >> 4) * 8;
        #pragma unroll
        for (int i = 0; i < 8; i++)
            sW[f][lane * 8 + i] = f2bf(W_lin[(size_t)(k0 + i) * HC + n]);
    }
    if (threadIdx.x < HC) sB[threadIdx.x] = bc[threadIdx.x];
    __syncthreads();
    int w = threadIdx.x >> 6, lane = threadIdx.x & 63;
    int lhi = lane >> 4, llo = lane & 15;
    int tiles = (N + 63) >> 6;
    for (int tile = blockIdx.x; tile < tiles; tile += gridDim.x) {
        int nb = tile * 64 + w * 16;
        int arow = min(nb + llo, N - 1);
        const float* ap = agg + (size_t)arow * HC;
        bf16x8 Ah[2][2], Al[2][2];
        #pragma unroll
        for (int h = 0; h < 2; h++)
            #pragma unroll
            for (int kt = 0; kt < 2; kt++) {
                float x8[8];
                *(f32x4*)&x8[0] = *(const f32x4*)(ap + h * 64 + kt * 32 + lhi * 8);
                *(f32x4*)&x8[4] = *(const f32x4*)(ap + h * 64 + kt * 32 + lhi * 8 + 4);
                cvt_hilo8(x8, Ah[h][kt], Al[h][kt]);
            }
        f32x4 acc[2][4];
        #pragma unroll
        for (int h = 0; h < 2; h++)
            #pragma unroll
            for (int nt = 0; nt < 4; nt++) {
                float b = sB[h * 64 + nt * 16 + llo];
                acc[h][nt][0] = b; acc[h][nt][1] = b;
                acc[h][nt][2] = b; acc[h][nt][3] = b;
            }
        #pragma unroll
        for (int h = 0; h < 2; h++)
            #pragma unroll
            for (int kt = 0; kt < 2; kt++)
                #pragma unroll
                for (int nt = 0; nt < 4; nt++) {
                    bf16x8 b = *(const bf16x8*)&sW[h * 8 + kt * 4 + nt][lane * 8];
                    acc[h][nt] = __builtin_amdgcn_mfma_f32_16x16x32_bf16(Al[h][kt], b, acc[h][nt], 0, 0, 0);
                    acc[h][nt] = __builtin_amdgcn_mfma_f32_16x16x32_bf16(Ah[h][kt], b, acc[h][nt], 0, 0, 0);
                }
        #pragma unroll
        for (int h = 0; h < 2; h++)
            #pragma unroll
            for (int nt = 0; nt < 4; nt++)
                #pragma unroll
                for (int j = 0; j < 4; j++) {
                    int node = nb + 4 * lhi + j;
                    if (node < N)
                        agg[(size_t)node * HC + h * 64 + nt * 16 + llo] =
                            fmaxf(acc[h][nt][j], 0.f);
                }
    }
}

// ---- KP2 (MFMA): out = [left, (relu(t0@Wlt+blt))@Wfm+bfm] @ Wpc + bpc ----
__global__ __launch_bounds__(256) void k_tail_mfma(
    const float* __restrict__ t0, const float* __restrict__ left,
    const float* __restrict__ W_lt, const float* __restrict__ b_lt,
    const float* __restrict__ W_fm, const float* __restrict__ b_fm,
    const float* __restrict__ W_pc, const float* __restrict__ b_pc,
    float* __restrict__ out, int N)
{
    __shared__ __align__(16) ushort16 sWlt[16][512];  // 16KB
    __shared__ __align__(16) ushort16 sWfm[8][512];   // 8KB
    __shared__ __align__(16) ushort16 sWpT[8][512];   // 8KB
    __shared__ __align__(16) ushort16 sWpB[8][512];   // 8KB
    __shared__ __align__(16) float sX[4][1024];       // 16KB, per-wave swizzled
    __shared__ float sblt[CC], sbfm[CC], sbpc[CC];
    for (int t = threadIdx.x; t < 16 * 64; t += 256) {
        int lane = t & 63, f = t >> 6, nt = f & 3, kt = f >> 2;
        int n = nt * 16 + (lane & 15), k0 = kt * 32 + (lane >> 4) * 8;
        #pragma unroll
        for (int i = 0; i < 8; i++)
            sWlt[f][lane * 8 + i] = f2bf(W_lt[(k0 + i) * CC + n]);
    }
    for (int t = threadIdx.x; t < 8 * 64; t += 256) {
        int lane = t & 63, f = t >> 6, nt = f & 3, kt = f >> 2;
        int n = nt * 16 + (lane & 15), k0 = kt * 32 + (lane >> 4) * 8;
        #pragma unroll
        for (int i = 0; i < 8; i++) {
            sWfm[f][lane * 8 + i] = f2bf(W_fm[(k0 + i) * CC + n]);
            sWpT[f][lane * 8 + i] = f2bf(W_pc[(k0 + i) * CC + n]);
            sWpB[f][lane * 8 + i] = f2bf(W_pc[(64 + k0 + i) * CC + n]);
        }
    }
    if (threadIdx.x < CC) {
        sblt[threadIdx.x] = b_lt[threadIdx.x];
        sbfm[threadIdx.x] = b_fm[threadIdx.x];
        sbpc[threadIdx.x] = b_pc[threadIdx.x];
    }
    __syncthreads();
    int w = threadIdx.x >> 6, lane = threadIdx.x & 63;
    int lhi = lane >> 4, llo = lane & 15;
    float* xw = &sX[w][0];
    int swz = (llo & 7) << 2;          // read-side swizzle (row = llo)
    int tiles = (N + 63) >> 6;
    for (int tile = blockIdx.x; tile < tiles; tile += gridDim.x) {
        int nb = tile * 64 + w * 16;
        int arow = min(nb + llo, N - 1);
        // ---- layer2: X1 = relu(t0 @ Wlt + blt)
        f32x4 acc2[4];
        #pragma unroll
        for (int nt = 0; nt < 4; nt++) {
            float b = sblt[nt * 16 + llo];
            acc2[nt][0] = b; acc2[nt][1] = b; acc2[nt][2] = b; acc2[nt][3] = b;
        }
        const float* tp = t0 + (size_t)arow * HC;
        #pragma unroll
        for (int kt = 0; kt < 4; kt++) {
            float x8[8];
            *(f32x4*)&x8[0] = *(const f32x4*)(tp + kt * 32 + lhi * 8);
            *(f32x4*)&x8[4] = *(const f32x4*)(tp + kt * 32 + lhi * 8 + 4);
            bf16x8 ah, al; cvt_hilo8(x8, ah, al);
            #pragma unroll
            for (int nt = 0; nt < 4; nt++) {
                bf16x8 b = *(const bf16x8*)&sWlt[kt * 4 + nt][lane * 8];
                acc2[nt] = __builtin_amdgcn_mfma_f32_16x16x32_bf16(al, b, acc2[nt], 0, 0, 0);
                acc2[nt] = __builtin_amdgcn_mfma_f32_16x16x32_bf16(ah, b, acc2[nt], 0, 0, 0);
            }
        }
        #pragma unroll
        for (int nt = 0; nt < 4; nt++)
            #pragma unroll
            for (int j = 0; j < 4; j++) {
                int row = 4 * lhi + j, col = nt * 16 + llo;
                xw[row * 64 + (col ^ ((row & 7) << 2))] = fmaxf(acc2[nt][j], 0.f);
            }
        // ---- layer3: X2 = X1 @ Wfm + bfm (no relu)
        f32x4 acc3[4];
        #pragma unroll
        for (int nt = 0; nt < 4; nt++) {
            float b = sbfm[nt * 16 + llo];
            acc3[nt][0] = b; acc3[nt][1] = b; acc3[nt][2] = b; acc3[nt][3] = b;
        }
        #pragma unroll
        for (int kt = 0; kt < 2; kt++) {
            int k0 = kt * 32 + lhi * 8;
            float x8[8];
            *(f32x4*)&x8[0] = *(const f32x4*)&xw[llo * 64 + ((k0    ) ^ swz)];
            *(f32x4*)&x8[4] = *(const f32x4*)&xw[llo * 64 + ((k0 + 4) ^ swz)];
            bf16x8 ah, al; cvt_hilo8(x8, ah, al);
            #pragma unroll
            for (int nt = 0; nt < 4; nt++) {
                bf16x8 b = *(const bf16x8*)&sWfm[kt * 4 + nt][lane * 8];
                acc3[nt] = __builtin_amdgcn_mfma_f32_16x16x32_bf16(al, b, acc3[nt], 0, 0, 0);
                acc3[nt] = __builtin_amdgcn_mfma_f32_16x16x32_bf16(ah, b, acc3[nt], 0, 0, 0);
            }
        }
        #pragma unroll
        for (int nt = 0; nt < 4; nt++)
            #pragma unroll
            for (int j = 0; j < 4; j++) {
                int row = 4 * lhi + j, col = nt * 16 + llo;
                xw[row * 64 + (col ^ ((row & 7) << 2))] = acc3[nt][j];
            }
        // ---- layer4: out = left @ WpcT + X2 @ WpcB + bpc
        f32x4 acc4[4];
        #pragma unroll
        for (int nt = 0; nt < 4; nt++) {
            float b = sbpc[nt * 16 + llo];
            acc4[nt][0] = b; acc4[nt][1] = b; acc4[nt][2] = b; acc4[nt][3] = b;
        }
        const float* lp = left + (size_t)arow * DD;
        #pragma unroll
        for (int kt = 0; kt < 2; kt++) {
            float x8[8];
            *(f32x4*)&x8[0] = *(const f32x4*)(lp + kt * 32 + lhi * 8);
            *(f32x4*)&x8[4] = *(const f32x4*)(lp + kt * 32 + lhi * 8 + 4);
            bf16x8 ah, al; cvt_hilo8(x8, ah, al);
            #pragma unroll
            for (int nt = 0; nt < 4; nt++) {
                bf16x8 b = *(const bf16x8*)&sWpT[kt * 4 + nt][lane * 8];
                acc4[nt] = __builtin_amdgcn_mfma_f32_16x16x32_bf16(al, b, acc4[nt], 0, 0, 0);
                acc4[nt] = __builtin_amdgcn_mfma_f32_16x16x32_bf16(ah, b, acc4[nt], 0, 0, 0);
            }
        }
        #pragma unroll
        for (int kt = 0; kt < 2; kt++) {
            int k0 = kt * 32 + lhi * 8;
            float x8[8];
            *(f32x4*)&x8[0] = *(const f32x4*)&xw[llo * 64 + ((k0    ) ^ swz)];
            *(f32x4*)&x8[4] = *(const f32x4*)&xw[llo * 64 + ((k0 + 4) ^ swz)];
            bf16x8 ah, al; cvt_hilo8(x8, ah, al);
            #pragma unroll
            for (int nt = 0; nt < 4; nt++) {
                bf16x8 b = *(const bf16x8*)&sWpB[kt * 4 + nt][lane * 8];
                acc4[nt] = __builtin_amdgcn_mfma_f32_16x16x32_bf16(al, b, acc4[nt], 0, 0, 0);
                acc4[nt] = __builtin_amdgcn_mfma_f32_16x16x32_bf16(ah, b, acc4[nt], 0, 0, 0);
            }
        }
        #pragma unroll
        for (int nt = 0; nt < 4; nt++)
            #pragma unroll
            for (int j = 0; j < 4; j++) {
                int node = nb + 4 * lhi + j;
                if (node < N)
                    out[(size_t)node * CC + nt * 16 + llo] = acc4[nt][j];
            }
    }
}

// ---- K6: edge_index -> float copy into output slot 1 ----
__global__ void k_copy_idx(const int* ei, float* out, int n) {
    for (int i = blockIdx.x * blockDim.x + threadIdx.x; i < n;
         i += gridDim.x * blockDim.x)
        out[i] = (float)ei[i];
}

extern "C" void kernel_launch(void* const* d_in, const int* in_sizes, int n_in,
                              void* d_out, int out_size, void* d_ws, size_t ws_size,
                              hipStream_t stream) {
    const float* left      = (const float*)d_in[0];
    const int*   ei        = (const int*)d_in[1];
    const float* efeat     = (const float*)d_in[2];
    const float* right     = (const float*)d_in[3];
    const float* W_lin     = (const float*)d_in[5];
    const float* att_src   = (const float*)d_in[6];
    const float* att_dst   = (const float*)d_in[7];
    const float* W_edge    = (const float*)d_in[8];
    const float* att_edge  = (const float*)d_in[9];
    const float* bias_conv = (const float*)d_in[10];
    const float* W_lt      = (const float*)d_in[11];
    const float* b_lt      = (const float*)d_in[12];
    const float* W_fm      = (const float*)d_in[13];
    const float* b_fm      = (const float*)d_in[14];
    const float* W_pc      = (const float*)d_in[15];
    const float* b_pc      = (const float*)d_in[16];

    const int N = in_sizes[0] / DD;     // 50000
    const int E = in_sizes[2] / DD;     // 800000
    const int NB = (N + 255) / 256;     // 196 scan blocks (must be <= 256)

    // ws layout (4B units):
    //   vfold 512 | a_src 2N | a_dst 2N | counts N | offs N | cursor N |
    //   bsum 256 | bpre 256 | sorted E | agg 128N            (~30.2 MB)
    float* ws     = (float*)d_ws;
    float* vfold  = ws;
    float* a_src  = ws + 512;
    float* a_dst  = a_src + 2 * (size_t)N;
    int*   counts = (int*)(a_dst + 2 * (size_t)N);
    int*   offs   = counts + N;
    int*   cursor = offs + N;
    int*   bsum   = cursor + N;
    int*   bpre   = bsum + 256;
    int*   sorted = bpre + 256;
    float* agg    = (float*)(sorted + E);
    (void)ws_size; (void)n_in; (void)out_size;

    float* out_lu   = (float*)d_out;                 // [N,64]
    float* out_ei   = out_lu + (size_t)N * CC;       // [2,E] as float
    float* att_slot = out_ei + (size_t)2 * E;        // [E,2]: alpha -> att

    hipMemsetAsync(counts, 0, (size_t)N * sizeof(int), stream);

    hipLaunchKernelGGL(k_fold, dim3(1), dim3(128), 0, stream,
                       W_lin, att_src, att_dst, W_edge, att_edge, vfold);
    hipLaunchKernelGGL(k_node_logits, dim3((N + 255) / 256), dim3(256), 0, stream,
                       right, left, vfold, a_src, a_dst, N);
    hipLaunchKernelGGL(k_edge_alpha, dim3((E + 255) / 256), dim3(256), 0, stream,
                       efeat, ei, vfold, a_src, a_dst, att_slot, counts, E, N);
    hipLaunchKernelGGL(k_scan1, dim3(NB), dim3(256), 0, stream,
                       counts, bsum, N);
    hipLaunchKernelGGL(k_scan2, dim3(1), dim3(256), 0, stream,
                       bsum, bpre, NB);
    hipLaunchKernelGGL(k_scan3, dim3(NB), dim3(256), 0, stream,
                       counts, bpre, offs, cursor, N);
    hipLaunchKernelGGL(k_ids, dim3((E + 255) / 256), dim3(256), 0, stream,
                       ei, cursor, sorted, E, N);
    hipLaunchKernelGGL(k_gather, dim3((N + 3) / 4), dim3(256), 0, stream,
                       ei, offs, counts, sorted, right, att_slot, agg, N);
    hipLaunchKernelGGL(k_lin_mfma, dim3(512), dim3(256), 0, stream,
                       W_lin, bias_conv, agg, N);
    hipLaunchKernelGGL(k_tail_mfma, dim3(512), dim3(256), 0, stream,
                       agg, left, W_lt, b_lt, W_fm, b_fm, W_pc, b_pc, out_lu, N);
    hipLaunchKernelGGL(k_copy_idx, dim3(1024), dim3(256), 0, stream,
                       ei, out_ei, 2 * E);
}

// Round 5
// 525.830 us; speedup vs baseline: 4.1309x; 1.0291x over previous
//
#include <hip/hip_runtime.h>
#include <hip/hip_bf16.h>

typedef unsigned int uint32;
typedef unsigned short ushort16;
typedef float f32x4 __attribute__((ext_vector_type(4)));
typedef short bf16x8 __attribute__((ext_vector_type(8)));

#define HH 2
#define CC 64
#define DD 64
#define HC 128

__device__ __forceinline__ float bf2f(ushort16 u) {
    union { float f; uint32 u; } x; x.u = ((uint32)u) << 16; return x.f;
}
__device__ __forceinline__ ushort16 f2bf(float f) {
    union { float f; uint32 u; } x; x.f = f;
    uint32 u = x.u;
    u += 0x7FFFu + ((u >> 16) & 1u);   // round-to-nearest-even
    return (ushort16)(u >> 16);
}
__device__ __forceinline__ int clampi(int v, int N) {
    return min(max(v, 0), N - 1);
}
__device__ __forceinline__ float dot4(f32x4 a, f32x4 b) {
    return a.x * b.x + a.y * b.y + a.z * b.z + a.w * b.w;
}
// split 8 floats into hi(truncated bf16) + lo(bf16 of residual): ~fp32 accuracy
__device__ __forceinline__ void cvt_hilo8(const float* x, bf16x8& hi, bf16x8& lo) {
    #pragma unroll
    for (int i = 0; i < 8; i++) {
        union { float f; uint32 u; } a; a.f = x[i];
        uint32 uh = a.u & 0xFFFF0000u;
        hi[i] = (short)(uh >> 16);
        union { float f; uint32 u; } hf; hf.u = uh;
        lo[i] = (short)f2bf(a.f - hf.f);
    }
}

// ---- K0: fold attention vectors into weight matrices ----
__global__ void k_fold(const float* W_lin, const float* att_src,
                       const float* att_dst, const float* W_edge,
                       const float* att_edge, float* vfold) {
    int t = threadIdx.x;            // 128 threads: t = h*64+d
    int h = t >> 6, d = t & 63;
    float vs = 0.f, vd = 0.f, ve = 0.f;
    for (int c = 0; c < CC; c++) {
        float wl = W_lin[d * HC + h * CC + c];
        vs += wl * att_src[h * CC + c];
        vd += wl * att_dst[h * CC + c];
        ve += W_edge[d * HC + h * CC + c] * att_edge[h * CC + c];
    }
    vfold[t] = vs; vfold[128 + t] = vd; vfold[256 + t] = ve;
}

// ---- K1: per-node logits, 16-lane group per node (contiguous 256B streams) ----
__global__ __launch_bounds__(256) void k_node_logits(
    const float* right, const float* left, const float* vfold,
    float* a_src, float* a_dst, int N)
{
    __shared__ float vs[HC], vd[HC];
    if (threadIdx.x < HC) {
        vs[threadIdx.x] = vfold[threadIdx.x];
        vd[threadIdx.x] = vfold[HC + threadIdx.x];
    }
    __syncthreads();
    int g = threadIdx.x >> 4, sub = threadIdx.x & 15;
    f32x4 s0 = *(const f32x4*)&vs[sub * 4];
    f32x4 s1 = *(const f32x4*)&vs[64 + sub * 4];
    f32x4 d0 = *(const f32x4*)&vd[sub * 4];
    f32x4 d1 = *(const f32x4*)&vd[64 + sub * 4];
    #pragma unroll
    for (int it = 0; it < 4; it++) {
        int n = blockIdx.x * 64 + it * 16 + g;
        if (n >= N) break;
        f32x4 r4 = *(const f32x4*)(right + (size_t)n * DD + sub * 4);
        f32x4 l4 = *(const f32x4*)(left  + (size_t)n * DD + sub * 4);
        float p0 = dot4(r4, s0), p1 = dot4(r4, s1);
        float q0 = dot4(l4, d0), q1 = dot4(l4, d1);
        #pragma unroll
        for (int m = 8; m >= 1; m >>= 1) {
            p0 += __shfl_xor(p0, m, 64); p1 += __shfl_xor(p1, m, 64);
            q0 += __shfl_xor(q0, m, 64); q1 += __shfl_xor(q1, m, 64);
        }
        if (sub == 0) {
            *(float2*)(a_src + (size_t)n * 2) = make_float2(p0, p1);
            *(float2*)(a_dst + (size_t)n * 2) = make_float2(q0, q1);
        }
    }
}

// ---- K2: 16-lane group per edge: alpha GEMV + leaky-relu + hist + idx-copy ----
__global__ __launch_bounds__(256) void k_edge_alpha(
    const float* edge_feat, const int* ei, const float* vfold,
    const float* a_src, const float* a_dst,
    float* att_slot, int* counts, float* out_ei, int E, int N)
{
    __shared__ float vE[HC];
    if (threadIdx.x < HC) vE[threadIdx.x] = vfold[256 + threadIdx.x];
    __syncthreads();
    int g = threadIdx.x >> 4, sub = threadIdx.x & 15;
    f32x4 w0 = *(const f32x4*)&vE[sub * 4];
    f32x4 w1 = *(const f32x4*)&vE[64 + sub * 4];
    #pragma unroll
    for (int it = 0; it < 4; it++) {
        int e = blockIdx.x * 64 + it * 16 + g;
        if (e >= E) break;
        f32x4 f = *(const f32x4*)(edge_feat + (size_t)e * DD + sub * 4);
        float p0 = dot4(f, w0), p1 = dot4(f, w1);
        #pragma unroll
        for (int m = 8; m >= 1; m >>= 1) {
            p0 += __shfl_xor(p0, m, 64); p1 += __shfl_xor(p1, m, 64);
        }
        if (sub == 0) {
            int raw_s = ei[e], raw_d = ei[E + e];
            int s  = clampi(raw_s, N);
            int d2 = clampi(raw_d, N);
            float2 asr = *(const float2*)(a_src + (size_t)s * 2);
            float2 ads = *(const float2*)(a_dst + (size_t)d2 * 2);
            float al0 = asr.x + ads.x + p0;
            float al1 = asr.y + ads.y + p1;
            al0 = (al0 > 0.f) ? al0 : 0.2f * al0;
            al1 = (al1 > 0.f) ? al1 : 0.2f * al1;
            *(float2*)(att_slot + (size_t)e * 2) = make_float2(al0, al1);
            atomicAdd(&counts[d2], 1);
            out_ei[e]     = (float)raw_s;
            out_ei[E + e] = (float)raw_d;
        }
    }
}

// ---- scan stage 1: per-block sums of counts ----
__global__ void k_scan1(const int* counts, int* bsum, int N) {
    int idx = blockIdx.x * 256 + threadIdx.x;
    int v = (idx < N) ? counts[idx] : 0;
    #pragma unroll
    for (int m = 32; m >= 1; m >>= 1) v += __shfl_xor(v, m, 64);
    __shared__ int wsum[4];
    if ((threadIdx.x & 63) == 0) wsum[threadIdx.x >> 6] = v;
    __syncthreads();
    if (threadIdx.x == 0) bsum[blockIdx.x] = wsum[0] + wsum[1] + wsum[2] + wsum[3];
}

// ---- scan stage 2: exclusive scan of block sums (NB <= 256) ----
__global__ void k_scan2(const int* bsum, int* bpre, int NB) {
    __shared__ int sh[256];
    int t = threadIdx.x;
    int v = (t < NB) ? bsum[t] : 0;
    sh[t] = v;
    __syncthreads();
    for (int off = 1; off < 256; off <<= 1) {
        int add = (t >= off) ? sh[t - off] : 0;
        __syncthreads();
        sh[t] += add;
        __syncthreads();
    }
    if (t < NB) bpre[t] = sh[t] - v;   // exclusive prefix
}

// ---- scan stage 3: per-element exclusive offsets; init cursor ----
__global__ void k_scan3(const int* counts, const int* bpre,
                        int* offs, int* cursor, int N) {
    __shared__ int sh[256];
    int t = threadIdx.x;
    int idx = blockIdx.x * 256 + t;
    int v = (idx < N) ? counts[idx] : 0;
    sh[t] = v;
    __syncthreads();
    for (int off = 1; off < 256; off <<= 1) {
        int add = (t >= off) ? sh[t - off] : 0;
        __syncthreads();
        sh[t] += add;
        __syncthreads();
    }
    if (idx < N) {
        int ex = bpre[blockIdx.x] + sh[t] - v;
        offs[idx] = ex;
        cursor[idx] = ex;
    }
}

// ---- scatter edge ids into dst-sorted order ----
__global__ void k_ids(const int* ei, int* cursor, int* sorted, int E, int N) {
    int e = blockIdx.x * 256 + threadIdx.x;
    if (e >= E) return;
    int d = clampi(ei[E + e], N);
    int pos = atomicAdd(&cursor[d], 1);
    sorted[pos] = e;
}

// ---- K4: per-dst-node ONLINE segment softmax + weighted gather-aggregate ----
// 16-lane group per node. Online (flash-style) max/sum: no pass-1 sweep, zero
// shuffles (dims lane-partitioned; m/s redundantly scalar). Branchless rescale.
__global__ __launch_bounds__(256) void k_gather(
    const int* ei, const int* offs, const int* counts, const int* sorted,
    const float* right, float* att_slot, float* agg, int N)
{
    int g = threadIdx.x >> 4, sub = threadIdx.x & 15;
    int n = blockIdx.x * 16 + g;
    if (n >= N) return;
    int start = offs[n], deg = counts[n];
    float m0 = -1e30f, m1 = -1e30f, s0 = 0.f, s1 = 0.f;
    f32x4 acc0 = {0.f, 0.f, 0.f, 0.f}, acc1 = {0.f, 0.f, 0.f, 0.f};
    for (int i = 0; i < deg; i++) {
        int e = sorted[start + i];                         // group-broadcast
        float2 a = *(const float2*)(att_slot + (size_t)e * 2);
        int si = clampi(ei[e], N);
        float nm0 = fmaxf(m0, a.x), nm1 = fmaxf(m1, a.y);
        float f0 = __expf(m0 - nm0), f1 = __expf(m1 - nm1);
        float e0 = __expf(a.x - nm0), e1 = __expf(a.y - nm1);
        f32x4 v = *(const f32x4*)(right + (size_t)si * DD + sub * 4);
        s0 = s0 * f0 + e0;  s1 = s1 * f1 + e1;
        acc0 = acc0 * f0 + e0 * v;
        acc1 = acc1 * f1 + e1 * v;
        m0 = nm0; m1 = nm1;
    }
    float inv0 = 1.f / (s0 + 1e-16f), inv1 = 1.f / (s1 + 1e-16f);
    // normalize att in place (lane-parallel over the segment)
    for (int i = sub; i < deg; i += 16) {
        int e = sorted[start + i];
        float2 a = *(const float2*)(att_slot + (size_t)e * 2);
        a.x = __expf(a.x - m0) * inv0;
        a.y = __expf(a.y - m1) * inv1;
        *(float2*)(att_slot + (size_t)e * 2) = a;
    }
    *(f32x4*)(agg + (size_t)n * HC + sub * 4)      = acc0 * inv0;
    *(f32x4*)(agg + (size_t)n * HC + 64 + sub * 4) = acc1 * inv1;
}

// ---- KP1 (MFMA): t0 = relu(agg @ Wlin_blockdiag + bc), IN PLACE over agg ----
__global__ __launch_bounds__(256) void k_lin_mfma(
    const float* __restrict__ W_lin, const float* __restrict__ bc,
    float* agg, int N)
{
    __shared__ __align__(16) ushort16 sW[16][512];  // [h*8+kt*4+nt][lane*8+i]  16KB
    __shared__ float sB[HC];
    for (int t = threadIdx.x; t < 16 * 64; t += 256) {
        int lane = t & 63, f = t >> 6;
        int nt = f & 3, kt = (f >> 2) & 1, h = f >> 3;
        int n = h * CC + nt * 16 + (lane & 15);
        int k0 = kt * 32 + (lane >> 4) * 8;
        #pragma unroll
        for (int i = 0; i < 8; i++)
            sW[f][lane * 8 + i] = f2bf(W_lin[(size_t)(k0 + i) * HC + n]);
    }
    if (threadIdx.x < HC) sB[threadIdx.x] = bc[threadIdx.x];
    __syncthreads();
    int w = threadIdx.x >> 6, lane = threadIdx.x & 63;
    int lhi = lane >> 4, llo = lane & 15;
    int tiles = (N + 63) >> 6;
    for (int tile = blockIdx.x; tile < tiles; tile += gridDim.x) {
        int nb = tile * 64 + w * 16;
        int arow = min(nb + llo, N - 1);
        const float* ap = agg + (size_t)arow * HC;
        bf16x8 Ah[2][2], Al[2][2];
        #pragma unroll
        for (int h = 0; h < 2; h++)
            #pragma unroll
            for (int kt = 0; kt < 2; kt++) {
                float x8[8];
                *(f32x4*)&x8[0] = *(const f32x4*)(ap + h * 64 + kt * 32 + lhi * 8);
                *(f32x4*)&x8[4] = *(const f32x4*)(ap + h * 64 + kt * 32 + lhi * 8 + 4);
                cvt_hilo8(x8, Ah[h][kt], Al[h][kt]);
            }
        f32x4 acc[2][4];
        #pragma unroll
        for (int h = 0; h < 2; h++)
            #pragma unroll
            for (int nt = 0; nt < 4; nt++) {
                float b = sB[h * 64 + nt * 16 + llo];
                acc[h][nt][0] = b; acc[h][nt][1] = b;
                acc[h][nt][2] = b; acc[h][nt][3] = b;
            }
        #pragma unroll
        for (int h = 0; h < 2; h++)
            #pragma unroll
            for (int kt = 0; kt < 2; kt++)
                #pragma unroll
                for (int nt = 0; nt < 4; nt++) {
                    bf16x8 b = *(const bf16x8*)&sW[h * 8 + kt * 4 + nt][lane * 8];
                    acc[h][nt] = __builtin_amdgcn_mfma_f32_16x16x32_bf16(Al[h][kt], b, acc[h][nt], 0, 0, 0);
                    acc[h][nt] = __builtin_amdgcn_mfma_f32_16x16x32_bf16(Ah[h][kt], b, acc[h][nt], 0, 0, 0);
                }
        #pragma unroll
        for (int h = 0; h < 2; h++)
            #pragma unroll
            for (int nt = 0; nt < 4; nt++)
                #pragma unroll
                for (int j = 0; j < 4; j++) {
                    int node = nb + 4 * lhi + j;
                    if (node < N)
                        agg[(size_t)node * HC + h * 64 + nt * 16 + llo] =
                            fmaxf(acc[h][nt][j], 0.f);
                }
    }
}

// ---- KP2 (MFMA): out = [left, (relu(t0@Wlt+blt))@Wfm+bfm] @ Wpc + bpc ----
__global__ __launch_bounds__(256) void k_tail_mfma(
    const float* __restrict__ t0, const float* __restrict__ left,
    const float* __restrict__ W_lt, const float* __restrict__ b_lt,
    const float* __restrict__ W_fm, const float* __restrict__ b_fm,
    const float* __restrict__ W_pc, const float* __restrict__ b_pc,
    float* __restrict__ out, int N)
{
    __shared__ __align__(16) ushort16 sWlt[16][512];  // 16KB
    __shared__ __align__(16) ushort16 sWfm[8][512];   // 8KB
    __shared__ __align__(16) ushort16 sWpT[8][512];   // 8KB
    __shared__ __align__(16) ushort16 sWpB[8][512];   // 8KB
    __shared__ __align__(16) float sX[4][1024];       // 16KB, per-wave swizzled
    __shared__ float sblt[CC], sbfm[CC], sbpc[CC];
    for (int t = threadIdx.x; t < 16 * 64; t += 256) {
        int lane = t & 63, f = t >> 6, nt = f & 3, kt = f >> 2;
        int n = nt * 16 + (lane & 15), k0 = kt * 32 + (lane >> 4) * 8;
        #pragma unroll
        for (int i = 0; i < 8; i++)
            sWlt[f][lane * 8 + i] = f2bf(W_lt[(k0 + i) * CC + n]);
    }
    for (int t = threadIdx.x; t < 8 * 64; t += 256) {
        int lane = t & 63, f = t >> 6, nt = f & 3, kt = f >> 2;
        int n = nt * 16 + (lane & 15), k0 = kt * 32 + (lane >> 4) * 8;
        #pragma unroll
        for (int i = 0; i < 8; i++) {
            sWfm[f][lane * 8 + i] = f2bf(W_fm[(k0 + i) * CC + n]);
            sWpT[f][lane * 8 + i] = f2bf(W_pc[(k0 + i) * CC + n]);
            sWpB[f][lane * 8 + i] = f2bf(W_pc[(64 + k0 + i) * CC + n]);
        }
    }
    if (threadIdx.x < CC) {
        sblt[threadIdx.x] = b_lt[threadIdx.x];
        sbfm[threadIdx.x] = b_fm[threadIdx.x];
        sbpc[threadIdx.x] = b_pc[threadIdx.x];
    }
    __syncthreads();
    int w = threadIdx.x >> 6, lane = threadIdx.x & 63;
    int lhi = lane >> 4, llo = lane & 15;
    float* xw = &sX[w][0];
    int swz = (llo & 7) << 2;          // read-side swizzle (row = llo)
    int tiles = (N + 63) >> 6;
    for (int tile = blockIdx.x; tile < tiles; tile += gridDim.x) {
        int nb = tile * 64 + w * 16;
        int arow = min(nb + llo, N - 1);
        // ---- layer2: X1 = relu(t0 @ Wlt + blt)
        f32x4 acc2[4];
        #pragma unroll
        for (int nt = 0; nt < 4; nt++) {
            float b = sblt[nt * 16 + llo];
            acc2[nt][0] = b; acc2[nt][1] = b; acc2[nt][2] = b; acc2[nt][3] = b;
        }
        const float* tp = t0 + (size_t)arow * HC;
        #pragma unroll
        for (int kt = 0; kt < 4; kt++) {
            float x8[8];
            *(f32x4*)&x8[0] = *(const f32x4*)(tp + kt * 32 + lhi * 8);
            *(f32x4*)&x8[4] = *(const f32x4*)(tp + kt * 32 + lhi * 8 + 4);
            bf16x8 ah, al; cvt_hilo8(x8, ah, al);
            #pragma unroll
            for (int nt = 0; nt < 4; nt++) {
                bf16x8 b = *(const bf16x8*)&sWlt[kt * 4 + nt][lane * 8];
                acc2[nt] = __builtin_amdgcn_mfma_f32_16x16x32_bf16(al, b, acc2[nt], 0, 0, 0);
                acc2[nt] = __builtin_amdgcn_mfma_f32_16x16x32_bf16(ah, b, acc2[nt], 0, 0, 0);
            }
        }
        #pragma unroll
        for (int nt = 0; nt < 4; nt++)
            #pragma unroll
            for (int j = 0; j < 4; j++) {
                int row = 4 * lhi + j, col = nt * 16 + llo;
                xw[row * 64 + (col ^ ((row & 7) << 2))] = fmaxf(acc2[nt][j], 0.f);
            }
        // ---- layer3: X2 = X1 @ Wfm + bfm (no relu)
        f32x4 acc3[4];
        #pragma unroll
        for (int nt = 0; nt < 4; nt++) {
            float b = sbfm[nt * 16 + llo];
            acc3[nt][0] = b; acc3[nt][1] = b; acc3[nt][2] = b; acc3[nt][3] = b;
        }
        #pragma unroll
        for (int kt = 0; kt < 2; kt++) {
            int k0 = kt * 32 + lhi * 8;
            float x8[8];
            *(f32x4*)&x8[0] = *(const f32x4*)&xw[llo * 64 + ((k0    ) ^ swz)];
            *(f32x4*)&x8[4] = *(const f32x4*)&xw[llo * 64 + ((k0 + 4) ^ swz)];
            bf16x8 ah, al; cvt_hilo8(x8, ah, al);
            #pragma unroll
            for (int nt = 0; nt < 4; nt++) {
                bf16x8 b = *(const bf16x8*)&sWfm[kt * 4 + nt][lane * 8];
                acc3[nt] = __builtin_amdgcn_mfma_f32_16x16x32_bf16(al, b, acc3[nt], 0, 0, 0);
                acc3[nt] = __builtin_amdgcn_mfma_f32_16x16x32_bf16(ah, b, acc3[nt], 0, 0, 0);
            }
        }
        #pragma unroll
        for (int nt = 0; nt < 4; nt++)
            #pragma unroll
            for (int j = 0; j < 4; j++) {
                int row = 4 * lhi + j, col = nt * 16 + llo;
                xw[row * 64 + (col ^ ((row & 7) << 2))] = acc3[nt][j];
            }
        // ---- layer4: out = left @ WpcT + X2 @ WpcB + bpc
        f32x4 acc4[4];
        #pragma unroll
        for (int nt = 0; nt < 4; nt++) {
            float b = sbpc[nt * 16 + llo];
            acc4[nt][0] = b; acc4[nt][1] = b; acc4[nt][2] = b; acc4[nt][3] = b;
        }
        const float* lp = left + (size_t)arow * DD;
        #pragma unroll
        for (int kt = 0; kt < 2; kt++) {
            float x8[8];
            *(f32x4*)&x8[0] = *(const f32x4*)(lp + kt * 32 + lhi * 8);
            *(f32x4*)&x8[4] = *(const f32x4*)(lp + kt * 32 + lhi * 8 + 4);
            bf16x8 ah, al; cvt_hilo8(x8, ah, al);
            #pragma unroll
            for (int nt = 0; nt < 4; nt++) {
                bf16x8 b = *(const bf16x8*)&sWpT[kt * 4 + nt][lane * 8];
                acc4[nt] = __builtin_amdgcn_mfma_f32_16x16x32_bf16(al, b, acc4[nt], 0, 0, 0);
                acc4[nt] = __builtin_amdgcn_mfma_f32_16x16x32_bf16(ah, b, acc4[nt], 0, 0, 0);
            }
        }
        #pragma unroll
        for (int kt = 0; kt < 2; kt++) {
            int k0 = kt * 32 + lhi * 8;
            float x8[8];
            *(f32x4*)&x8[0] = *(const f32x4*)&xw[llo * 64 + ((k0    ) ^ swz)];
            *(f32x4*)&x8[4] = *(const f32x4*)&xw[llo * 64 + ((k0 + 4) ^ swz)];
            bf16x8 ah, al; cvt_hilo8(x8, ah, al);
            #pragma unroll
            for (int nt = 0; nt < 4; nt++) {
                bf16x8 b = *(const bf16x8*)&sWpB[kt * 4 + nt][lane * 8];
                acc4[nt] = __builtin_amdgcn_mfma_f32_16x16x32_bf16(al, b, acc4[nt], 0, 0, 0);
                acc4[nt] = __builtin_amdgcn_mfma_f32_16x16x32_bf16(ah, b, acc4[nt], 0, 0, 0);
            }
        }
        #pragma unroll
        for (int nt = 0; nt < 4; nt++)
            #pragma unroll
            for (int j = 0; j < 4; j++) {
                int node = nb + 4 * lhi + j;
                if (node < N)
                    out[(size_t)node * CC + nt * 16 + llo] = acc4[nt][j];
            }
    }
}

extern "C" void kernel_launch(void* const* d_in, const int* in_sizes, int n_in,
                              void* d_out, int out_size, void* d_ws, size_t ws_size,
                              hipStream_t stream) {
    const float* left      = (const float*)d_in[0];
    const int*   ei        = (const int*)d_in[1];
    const float* efeat     = (const float*)d_in[2];
    const float* right     = (const float*)d_in[3];
    const float* W_lin     = (const float*)d_in[5];
    const float* att_src   = (const float*)d_in[6];
    const float* att_dst   = (const float*)d_in[7];
    const float* W_edge    = (const float*)d_in[8];
    const float* att_edge  = (const float*)d_in[9];
    const float* bias_conv = (const float*)d_in[10];
    const float* W_lt      = (const float*)d_in[11];
    const float* b_lt      = (const float*)d_in[12];
    const float* b_fm      = (const float*)d_in[14];
    const float* W_fm      = (const float*)d_in[13];
    const float* W_pc      = (const float*)d_in[15];
    const float* b_pc      = (const float*)d_in[16];

    const int N = in_sizes[0] / DD;     // 50000
    const int E = in_sizes[2] / DD;     // 800000
    const int NB = (N + 255) / 256;     // 196 scan blocks (must be <= 256)

    // ws layout (4B units):
    //   vfold 512 | a_src 2N | a_dst 2N | counts N | offs N | cursor N |
    //   bsum 256 | bpre 256 | sorted E | agg 128N            (~30.2 MB)
    float* ws     = (float*)d_ws;
    float* vfold  = ws;
    float* a_src  = ws + 512;
    float* a_dst  = a_src + 2 * (size_t)N;
    int*   counts = (int*)(a_dst + 2 * (size_t)N);
    int*   offs   = counts + N;
    int*   cursor = offs + N;
    int*   bsum   = cursor + N;
    int*   bpre   = bsum + 256;
    int*   sorted = bpre + 256;
    float* agg    = (float*)(sorted + E);
    (void)ws_size; (void)n_in; (void)out_size;

    float* out_lu   = (float*)d_out;                 // [N,64]
    float* out_ei   = out_lu + (size_t)N * CC;       // [2,E] as float
    float* att_slot = out_ei + (size_t)2 * E;        // [E,2]: alpha -> att

    hipMemsetAsync(counts, 0, (size_t)N * sizeof(int), stream);

    hipLaunchKernelGGL(k_fold, dim3(1), dim3(128), 0, stream,
                       W_lin, att_src, att_dst, W_edge, att_edge, vfold);
    hipLaunchKernelGGL(k_node_logits, dim3((N + 63) / 64), dim3(256), 0, stream,
                       right, left, vfold, a_src, a_dst, N);
    hipLaunchKernelGGL(k_edge_alpha, dim3((E + 63) / 64), dim3(256), 0, stream,
                       efeat, ei, vfold, a_src, a_dst, att_slot, counts, out_ei,
                       E, N);
    hipLaunchKernelGGL(k_scan1, dim3(NB), dim3(256), 0, stream,
                       counts, bsum, N);
    hipLaunchKernelGGL(k_scan2, dim3(1), dim3(256), 0, stream,
                       bsum, bpre, NB);
    hipLaunchKernelGGL(k_scan3, dim3(NB), dim3(256), 0, stream,
                       counts, bpre, offs, cursor, N);
    hipLaunchKernelGGL(k_ids, dim3((E + 255) / 256), dim3(256), 0, stream,
                       ei, cursor, sorted, E, N);
    hipLaunchKernelGGL(k_gather, dim3((N + 15) / 16), dim3(256), 0, stream,
                       ei, offs, counts, sorted, right, att_slot, agg, N);
    hipLaunchKernelGGL(k_lin_mfma, dim3(512), dim3(256), 0, stream,
                       W_lin, bias_conv, agg, N);
    hipLaunchKernelGGL(k_tail_mfma, dim3(512), dim3(256), 0, stream,
                       agg, left, W_lt, b_lt, W_fm, b_fm, W_pc, b_pc, out_lu, N);
}

// Round 6
// 490.999 us; speedup vs baseline: 4.4239x; 1.0709x over previous
//
#include <hip/hip_runtime.h>
#include <hip/hip_bf16.h>

typedef unsigned int uint32;
typedef unsigned short ushort16;
typedef float f32x4 __attribute__((ext_vector_type(4)));
typedef short bf16x8 __attribute__((ext_vector_type(8)));

#define HH 2
#define CC 64
#define DD 64
#define HC 128

__device__ __forceinline__ float bf2f(ushort16 u) {
    union { float f; uint32 u; } x; x.u = ((uint32)u) << 16; return x.f;
}
__device__ __forceinline__ ushort16 f2bf(float f) {
    union { float f; uint32 u; } x; x.f = f;
    uint32 u = x.u;
    u += 0x7FFFu + ((u >> 16) & 1u);   // round-to-nearest-even
    return (ushort16)(u >> 16);
}
__device__ __forceinline__ int clampi(int v, int N) {
    return min(max(v, 0), N - 1);
}
__device__ __forceinline__ float dot4(f32x4 a, f32x4 b) {
    return a.x * b.x + a.y * b.y + a.z * b.z + a.w * b.w;
}
// split 8 floats into hi(truncated bf16) + lo(bf16 of residual): ~fp32 accuracy
__device__ __forceinline__ void cvt_hilo8(const float* x, bf16x8& hi, bf16x8& lo) {
    #pragma unroll
    for (int i = 0; i < 8; i++) {
        union { float f; uint32 u; } a; a.f = x[i];
        uint32 uh = a.u & 0xFFFF0000u;
        hi[i] = (short)(uh >> 16);
        union { float f; uint32 u; } hf; hf.u = uh;
        lo[i] = (short)f2bf(a.f - hf.f);
    }
}

// ---- K0: fold attention vectors into weight matrices ----
__global__ void k_fold(const float* W_lin, const float* att_src,
                       const float* att_dst, const float* W_edge,
                       const float* att_edge, float* vfold) {
    int t = threadIdx.x;            // 128 threads: t = h*64+d
    int h = t >> 6, d = t & 63;
    float vs = 0.f, vd = 0.f, ve = 0.f;
    for (int c = 0; c < CC; c++) {
        float wl = W_lin[d * HC + h * CC + c];
        vs += wl * att_src[h * CC + c];
        vd += wl * att_dst[h * CC + c];
        ve += W_edge[d * HC + h * CC + c] * att_edge[h * CC + c];
    }
    vfold[t] = vs; vfold[128 + t] = vd; vfold[256 + t] = ve;
}

// ---- K1: per-node logits, 16-lane group per node (contiguous 256B streams) ----
__global__ __launch_bounds__(256) void k_node_logits(
    const float* right, const float* left, const float* vfold,
    float* a_src, float* a_dst, int N)
{
    __shared__ float vs[HC], vd[HC];
    if (threadIdx.x < HC) {
        vs[threadIdx.x] = vfold[threadIdx.x];
        vd[threadIdx.x] = vfold[HC + threadIdx.x];
    }
    __syncthreads();
    int g = threadIdx.x >> 4, sub = threadIdx.x & 15;
    f32x4 s0 = *(const f32x4*)&vs[sub * 4];
    f32x4 s1 = *(const f32x4*)&vs[64 + sub * 4];
    f32x4 d0 = *(const f32x4*)&vd[sub * 4];
    f32x4 d1 = *(const f32x4*)&vd[64 + sub * 4];
    #pragma unroll
    for (int it = 0; it < 4; it++) {
        int n = blockIdx.x * 64 + it * 16 + g;
        if (n >= N) break;
        f32x4 r4 = *(const f32x4*)(right + (size_t)n * DD + sub * 4);
        f32x4 l4 = *(const f32x4*)(left  + (size_t)n * DD + sub * 4);
        float p0 = dot4(r4, s0), p1 = dot4(r4, s1);
        float q0 = dot4(l4, d0), q1 = dot4(l4, d1);
        #pragma unroll
        for (int m = 8; m >= 1; m >>= 1) {
            p0 += __shfl_xor(p0, m, 64); p1 += __shfl_xor(p1, m, 64);
            q0 += __shfl_xor(q0, m, 64); q1 += __shfl_xor(q1, m, 64);
        }
        if (sub == 0) {
            *(float2*)(a_src + (size_t)n * 2) = make_float2(p0, p1);
            *(float2*)(a_dst + (size_t)n * 2) = make_float2(q0, q1);
        }
    }
}

// ---- K2: 16-lane group per edge: alpha GEMV + leaky-relu + hist; coalesced
//      out_ei copy done block-wide at the end.
__global__ __launch_bounds__(256) void k_edge_alpha(
    const float* edge_feat, const int* ei, const float* vfold,
    const float* a_src, const float* a_dst,
    float* att_slot, int* counts, float* out_ei, int E, int N)
{
    __shared__ float vE[HC];
    if (threadIdx.x < HC) vE[threadIdx.x] = vfold[256 + threadIdx.x];
    __syncthreads();
    int g = threadIdx.x >> 4, sub = threadIdx.x & 15;
    f32x4 w0 = *(const f32x4*)&vE[sub * 4];
    f32x4 w1 = *(const f32x4*)&vE[64 + sub * 4];
    #pragma unroll
    for (int it = 0; it < 4; it++) {
        int e = blockIdx.x * 64 + it * 16 + g;
        if (e >= E) break;
        f32x4 f = *(const f32x4*)(edge_feat + (size_t)e * DD + sub * 4);
        float p0 = dot4(f, w0), p1 = dot4(f, w1);
        #pragma unroll
        for (int m = 8; m >= 1; m >>= 1) {
            p0 += __shfl_xor(p0, m, 64); p1 += __shfl_xor(p1, m, 64);
        }
        if (sub == 0) {
            int s  = clampi(ei[e], N);
            int d2 = clampi(ei[E + e], N);
            float2 asr = *(const float2*)(a_src + (size_t)s * 2);
            float2 ads = *(const float2*)(a_dst + (size_t)d2 * 2);
            float al0 = asr.x + ads.x + p0;
            float al1 = asr.y + ads.y + p1;
            al0 = (al0 > 0.f) ? al0 : 0.2f * al0;
            al1 = (al1 > 0.f) ? al1 : 0.2f * al1;
            *(float2*)(att_slot + (size_t)e * 2) = make_float2(al0, al1);
            atomicAdd(&counts[d2], 1);
        }
    }
    // coalesced edge_index -> float copy (64 src + 64 dst per block)
    int t = threadIdx.x, base = blockIdx.x * 64;
    if (t < 64) {
        int i = base + t;
        if (i < E) out_ei[i] = (float)ei[i];
    } else if (t < 128) {
        int i = base + (t - 64);
        if (i < E) out_ei[E + i] = (float)ei[E + i];
    }
}

// ---- scan stage 1: per-block sums of counts ----
__global__ void k_scan1(const int* counts, int* bsum, int N) {
    int idx = blockIdx.x * 256 + threadIdx.x;
    int v = (idx < N) ? counts[idx] : 0;
    #pragma unroll
    for (int m = 32; m >= 1; m >>= 1) v += __shfl_xor(v, m, 64);
    __shared__ int wsum[4];
    if ((threadIdx.x & 63) == 0) wsum[threadIdx.x >> 6] = v;
    __syncthreads();
    if (threadIdx.x == 0) bsum[blockIdx.x] = wsum[0] + wsum[1] + wsum[2] + wsum[3];
}

// ---- scan stage 2: exclusive scan of block sums (NB <= 256) ----
__global__ void k_scan2(const int* bsum, int* bpre, int NB) {
    __shared__ int sh[256];
    int t = threadIdx.x;
    int v = (t < NB) ? bsum[t] : 0;
    sh[t] = v;
    __syncthreads();
    for (int off = 1; off < 256; off <<= 1) {
        int add = (t >= off) ? sh[t - off] : 0;
        __syncthreads();
        sh[t] += add;
        __syncthreads();
    }
    if (t < NB) bpre[t] = sh[t] - v;   // exclusive prefix
}

// ---- scan stage 3: per-element exclusive offsets; init cursor ----
__global__ void k_scan3(const int* counts, const int* bpre,
                        int* offs, int* cursor, int N) {
    __shared__ int sh[256];
    int t = threadIdx.x;
    int idx = blockIdx.x * 256 + t;
    int v = (idx < N) ? counts[idx] : 0;
    sh[t] = v;
    __syncthreads();
    for (int off = 1; off < 256; off <<= 1) {
        int add = (t >= off) ? sh[t - off] : 0;
        __syncthreads();
        sh[t] += add;
        __syncthreads();
    }
    if (idx < N) {
        int ex = bpre[blockIdx.x] + sh[t] - v;
        offs[idx] = ex;
        cursor[idx] = ex;
    }
}

// ---- K3: scatter edge PAYLOAD (alpha0, alpha1, src, e) into dst-sorted order.
// Gather then reads contiguous 16B records instead of random att/ei gathers.
__global__ void k_ids(const int* ei, const float* att_slot, int* cursor,
                      float4* payload, int E, int N) {
    int e = blockIdx.x * 256 + threadIdx.x;
    if (e >= E) return;
    int s = clampi(ei[e], N);
    int d = clampi(ei[E + e], N);
    float2 a = *(const float2*)(att_slot + (size_t)e * 2);
    int pos = atomicAdd(&cursor[d], 1);
    payload[pos] = make_float4(a.x, a.y, __int_as_float(s), __int_as_float(e));
}

// ---- K4: per-dst-node ONLINE segment softmax + gather-aggregate, 4 edges/iter.
// 16-lane group per node. Payload stream is contiguous; 4 independent
// right-row gathers in flight per iteration. Branchless batched rescale
// (clamped duplicate reads keep the max correct; masked weights zero tails).
__global__ __launch_bounds__(256) void k_gather(
    const float4* payload, const int* offs, const int* counts,
    const float* right, float* att_slot, float* agg, int N)
{
    int g = threadIdx.x >> 4, sub = threadIdx.x & 15;
    int n = blockIdx.x * 16 + g;
    if (n >= N) return;
    int start = offs[n], deg = counts[n];
    float m0 = -1e30f, m1 = -1e30f, s0 = 0.f, s1 = 0.f;
    f32x4 acc0 = {0.f, 0.f, 0.f, 0.f}, acc1 = {0.f, 0.f, 0.f, 0.f};
    for (int base = 0; base < deg; base += 4) {
        int last = deg - 1;
        float4 p0 = payload[start + min(base,     last)];
        float4 p1 = payload[start + min(base + 1, last)];
        float4 p2 = payload[start + min(base + 2, last)];
        float4 p3 = payload[start + min(base + 3, last)];
        float k1 = (base + 1 < deg) ? 1.f : 0.f;
        float k2 = (base + 2 < deg) ? 1.f : 0.f;
        float k3 = (base + 3 < deg) ? 1.f : 0.f;
        // 4 independent row gathers in flight
        f32x4 v0 = *(const f32x4*)(right + (size_t)__float_as_int(p0.z) * DD + sub * 4);
        f32x4 v1 = *(const f32x4*)(right + (size_t)__float_as_int(p1.z) * DD + sub * 4);
        f32x4 v2 = *(const f32x4*)(right + (size_t)__float_as_int(p2.z) * DD + sub * 4);
        f32x4 v3 = *(const f32x4*)(right + (size_t)__float_as_int(p3.z) * DD + sub * 4);
        float bm0 = fmaxf(fmaxf(p0.x, p1.x), fmaxf(p2.x, p3.x));
        float bm1 = fmaxf(fmaxf(p0.y, p1.y), fmaxf(p2.y, p3.y));
        float nm0 = fmaxf(m0, bm0), nm1 = fmaxf(m1, bm1);
        float f0 = __expf(m0 - nm0), f1 = __expf(m1 - nm1);
        float e00 = __expf(p0.x - nm0),      e10 = __expf(p0.y - nm1);
        float e01 = __expf(p1.x - nm0) * k1, e11 = __expf(p1.y - nm1) * k1;
        float e02 = __expf(p2.x - nm0) * k2, e12 = __expf(p2.y - nm1) * k2;
        float e03 = __expf(p3.x - nm0) * k3, e13 = __expf(p3.y - nm1) * k3;
        s0 = s0 * f0 + (e00 + e01 + e02 + e03);
        s1 = s1 * f1 + (e10 + e11 + e12 + e13);
        acc0 = acc0 * f0 + e00 * v0 + e01 * v1 + e02 * v2 + e03 * v3;
        acc1 = acc1 * f1 + e10 * v0 + e11 * v1 + e12 * v2 + e13 * v3;
        m0 = nm0; m1 = nm1;
    }
    float inv0 = 1.f / (s0 + 1e-16f), inv1 = 1.f / (s1 + 1e-16f);
    // normalize att (contiguous payload reads; scattered 8B writes)
    for (int i = sub; i < deg; i += 16) {
        float4 p = payload[start + i];
        int e = __float_as_int(p.w);
        *(float2*)(att_slot + (size_t)e * 2) =
            make_float2(__expf(p.x - m0) * inv0, __expf(p.y - m1) * inv1);
    }
    *(f32x4*)(agg + (size_t)n * HC + sub * 4)      = acc0 * inv0;
    *(f32x4*)(agg + (size_t)n * HC + 64 + sub * 4) = acc1 * inv1;
}

// ---- KP1 (MFMA): t0 = relu(agg @ Wlin_blockdiag + bc), IN PLACE over agg ----
__global__ __launch_bounds__(256) void k_lin_mfma(
    const float* __restrict__ W_lin, const float* __restrict__ bc,
    float* agg, int N)
{
    __shared__ __align__(16) ushort16 sW[16][512];  // [h*8+kt*4+nt][lane*8+i]  16KB
    __shared__ float sB[HC];
    for (int t = threadIdx.x; t < 16 * 64; t += 256) {
        int lane = t & 63, f = t >> 6;
        int nt = f & 3, kt = (f >> 2) & 1, h = f >> 3;
        int n = h * CC + nt * 16 + (lane & 15);
        int k0 = kt * 32 + (lane >> 4) * 8;
        #pragma unroll
        for (int i = 0; i < 8; i++)
            sW[f][lane * 8 + i] = f2bf(W_lin[(size_t)(k0 + i) * HC + n]);
    }
    if (threadIdx.x < HC) sB[threadIdx.x] = bc[threadIdx.x];
    __syncthreads();
    int w = threadIdx.x >> 6, lane = threadIdx.x & 63;
    int lhi = lane >> 4, llo = lane & 15;
    int tiles = (N + 63) >> 6;
    for (int tile = blockIdx.x; tile < tiles; tile += gridDim.x) {
        int nb = tile * 64 + w * 16;
        int arow = min(nb + llo, N - 1);
        const float* ap = agg + (size_t)arow * HC;
        bf16x8 Ah[2][2], Al[2][2];
        #pragma unroll
        for (int h = 0; h < 2; h++)
            #pragma unroll
            for (int kt = 0; kt < 2; kt++) {
                float x8[8];
                *(f32x4*)&x8[0] = *(const f32x4*)(ap + h * 64 + kt * 32 + lhi * 8);
                *(f32x4*)&x8[4] = *(const f32x4*)(ap + h * 64 + kt * 32 + lhi * 8 + 4);
                cvt_hilo8(x8, Ah[h][kt], Al[h][kt]);
            }
        f32x4 acc[2][4];
        #pragma unroll
        for (int h = 0; h < 2; h++)
            #pragma unroll
            for (int nt = 0; nt < 4; nt++) {
                float b = sB[h * 64 + nt * 16 + llo];
                acc[h][nt][0] = b; acc[h][nt][1] = b;
                acc[h][nt][2] = b; acc[h][nt][3] = b;
            }
        #pragma unroll
        for (int h = 0; h < 2; h++)
            #pragma unroll
            for (int kt = 0; kt < 2; kt++)
                #pragma unroll
                for (int nt = 0; nt < 4; nt++) {
                    bf16x8 b = *(const bf16x8*)&sW[h * 8 + kt * 4 + nt][lane * 8];
                    acc[h][nt] = __builtin_amdgcn_mfma_f32_16x16x32_bf16(Al[h][kt], b, acc[h][nt], 0, 0, 0);
                    acc[h][nt] = __builtin_amdgcn_mfma_f32_16x16x32_bf16(Ah[h][kt], b, acc[h][nt], 0, 0, 0);
                }
        #pragma unroll
        for (int h = 0; h < 2; h++)
            #pragma unroll
            for (int nt = 0; nt < 4; nt++)
                #pragma unroll
                for (int j = 0; j < 4; j++) {
                    int node = nb + 4 * lhi + j;
                    if (node < N)
                        agg[(size_t)node * HC + h * 64 + nt * 16 + llo] =
                            fmaxf(acc[h][nt][j], 0.f);
                }
    }
}

// ---- KP2 (MFMA): out = [left, (relu(t0@Wlt+blt))@Wfm+bfm] @ Wpc + bpc ----
__global__ __launch_bounds__(256) void k_tail_mfma(
    const float* __restrict__ t0, const float* __restrict__ left,
    const float* __restrict__ W_lt, const float* __restrict__ b_lt,
    const float* __restrict__ W_fm, const float* __restrict__ b_fm,
    const float* __restrict__ W_pc, const float* __restrict__ b_pc,
    float* __restrict__ out, int N)
{
    __shared__ __align__(16) ushort16 sWlt[16][512];  // 16KB
    __shared__ __align__(16) ushort16 sWfm[8][512];   // 8KB
    __shared__ __align__(16) ushort16 sWpT[8][512];   // 8KB
    __shared__ __align__(16) ushort16 sWpB[8][512];   // 8KB
    __shared__ __align__(16) float sX[4][1024];       // 16KB, per-wave swizzled
    __shared__ float sblt[CC], sbfm[CC], sbpc[CC];
    for (int t = threadIdx.x; t < 16 * 64; t += 256) {
        int lane = t & 63, f = t >> 6, nt = f & 3, kt = f >> 2;
        int n = nt * 16 + (lane & 15), k0 = kt * 32 + (lane >> 4) * 8;
        #pragma unroll
        for (int i = 0; i < 8; i++)
            sWlt[f][lane * 8 + i] = f2bf(W_lt[(k0 + i) * CC + n]);
    }
    for (int t = threadIdx.x; t < 8 * 64; t += 256) {
        int lane = t & 63, f = t >> 6, nt = f & 3, kt = f >> 2;
        int n = nt * 16 + (lane & 15), k0 = kt * 32 + (lane >> 4) * 8;
        #pragma unroll
        for (int i = 0; i < 8; i++) {
            sWfm[f][lane * 8 + i] = f2bf(W_fm[(k0 + i) * CC + n]);
            sWpT[f][lane * 8 + i] = f2bf(W_pc[(k0 + i) * CC + n]);
            sWpB[f][lane * 8 + i] = f2bf(W_pc[(64 + k0 + i) * CC + n]);
        }
    }
    if (threadIdx.x < CC) {
        sblt[threadIdx.x] = b_lt[threadIdx.x];
        sbfm[threadIdx.x] = b_fm[threadIdx.x];
        sbpc[threadIdx.x] = b_pc[threadIdx.x];
    }
    __syncthreads();
    int w = threadIdx.x >> 6, lane = threadIdx.x & 63;
    int lhi = lane >> 4, llo = lane & 15;
    float* xw = &sX[w][0];
    int swz = (llo & 7) << 2;          // read-side swizzle (row = llo)
    int tiles = (N + 63) >> 6;
    for (int tile = blockIdx.x; tile < tiles; tile += gridDim.x) {
        int nb = tile * 64 + w * 16;
        int arow = min(nb + llo, N - 1);
        // ---- layer2: X1 = relu(t0 @ Wlt + blt)
        f32x4 acc2[4];
        #pragma unroll
        for (int nt = 0; nt < 4; nt++) {
            float b = sblt[nt * 16 + llo];
            acc2[nt][0] = b; acc2[nt][1] = b; acc2[nt][2] = b; acc2[nt][3] = b;
        }
        const float* tp = t0 + (size_t)arow * HC;
        #pragma unroll
        for (int kt = 0; kt < 4; kt++) {
            float x8[8];
            *(f32x4*)&x8[0] = *(const f32x4*)(tp + kt * 32 + lhi * 8);
            *(f32x4*)&x8[4] = *(const f32x4*)(tp + kt * 32 + lhi * 8 + 4);
            bf16x8 ah, al; cvt_hilo8(x8, ah, al);
            #pragma unroll
            for (int nt = 0; nt < 4; nt++) {
                bf16x8 b = *(const bf16x8*)&sWlt[kt * 4 + nt][lane * 8];
                acc2[nt] = __builtin_amdgcn_mfma_f32_16x16x32_bf16(al, b, acc2[nt], 0, 0, 0);
                acc2[nt] = __builtin_amdgcn_mfma_f32_16x16x32_bf16(ah, b, acc2[nt], 0, 0, 0);
            }
        }
        #pragma unroll
        for (int nt = 0; nt < 4; nt++)
            #pragma unroll
            for (int j = 0; j < 4; j++) {
                int row = 4 * lhi + j, col = nt * 16 + llo;
                xw[row * 64 + (col ^ ((row & 7) << 2))] = fmaxf(acc2[nt][j], 0.f);
            }
        // ---- layer3: X2 = X1 @ Wfm + bfm (no relu)
        f32x4 acc3[4];
        #pragma unroll
        for (int nt = 0; nt < 4; nt++) {
            float b = sbfm[nt * 16 + llo];
            acc3[nt][0] = b; acc3[nt][1] = b; acc3[nt][2] = b; acc3[nt][3] = b;
        }
        #pragma unroll
        for (int kt = 0; kt < 2; kt++) {
            int k0 = kt * 32 + lhi * 8;
            float x8[8];
            *(f32x4*)&x8[0] = *(const f32x4*)&xw[llo * 64 + ((k0    ) ^ swz)];
            *(f32x4*)&x8[4] = *(const f32x4*)&xw[llo * 64 + ((k0 + 4) ^ swz)];
            bf16x8 ah, al; cvt_hilo8(x8, ah, al);
            #pragma unroll
            for (int nt = 0; nt < 4; nt++) {
                bf16x8 b = *(const bf16x8*)&sWfm[kt * 4 + nt][lane * 8];
                acc3[nt] = __builtin_amdgcn_mfma_f32_16x16x32_bf16(al, b, acc3[nt], 0, 0, 0);
                acc3[nt] = __builtin_amdgcn_mfma_f32_16x16x32_bf16(ah, b, acc3[nt], 0, 0, 0);
            }
        }
        #pragma unroll
        for (int nt = 0; nt < 4; nt++)
            #pragma unroll
            for (int j = 0; j < 4; j++) {
                int row = 4 * lhi + j, col = nt * 16 + llo;
                xw[row * 64 + (col ^ ((row & 7) << 2))] = acc3[nt][j];
            }
        // ---- layer4: out = left @ WpcT + X2 @ WpcB + bpc
        f32x4 acc4[4];
        #pragma unroll
        for (int nt = 0; nt < 4; nt++) {
            float b = sbpc[nt * 16 + llo];
            acc4[nt][0] = b; acc4[nt][1] = b; acc4[nt][2] = b; acc4[nt][3] = b;
        }
        const float* lp = left + (size_t)arow * DD;
        #pragma unroll
        for (int kt = 0; kt < 2; kt++) {
            float x8[8];
            *(f32x4*)&x8[0] = *(const f32x4*)(lp + kt * 32 + lhi * 8);
            *(f32x4*)&x8[4] = *(const f32x4*)(lp + kt * 32 + lhi * 8 + 4);
            bf16x8 ah, al; cvt_hilo8(x8, ah, al);
            #pragma unroll
            for (int nt = 0; nt < 4; nt++) {
                bf16x8 b = *(const bf16x8*)&sWpT[kt * 4 + nt][lane * 8];
                acc4[nt] = __builtin_amdgcn_mfma_f32_16x16x32_bf16(al, b, acc4[nt], 0, 0, 0);
                acc4[nt] = __builtin_amdgcn_mfma_f32_16x16x32_bf16(ah, b, acc4[nt], 0, 0, 0);
            }
        }
        #pragma unroll
        for (int kt = 0; kt < 2; kt++) {
            int k0 = kt * 32 + lhi * 8;
            float x8[8];
            *(f32x4*)&x8[0] = *(const f32x4*)&xw[llo * 64 + ((k0    ) ^ swz)];
            *(f32x4*)&x8[4] = *(const f32x4*)&xw[llo * 64 + ((k0 + 4) ^ swz)];
            bf16x8 ah, al; cvt_hilo8(x8, ah, al);
            #pragma unroll
            for (int nt = 0; nt < 4; nt++) {
                bf16x8 b = *(const bf16x8*)&sWpB[kt * 4 + nt][lane * 8];
                acc4[nt] = __builtin_amdgcn_mfma_f32_16x16x32_bf16(al, b, acc4[nt], 0, 0, 0);
                acc4[nt] = __builtin_amdgcn_mfma_f32_16x16x32_bf16(ah, b, acc4[nt], 0, 0, 0);
            }
        }
        #pragma unroll
        for (int nt = 0; nt < 4; nt++)
            #pragma unroll
            for (int j = 0; j < 4; j++) {
                int node = nb + 4 * lhi + j;
                if (node < N)
                    out[(size_t)node * CC + nt * 16 + llo] = acc4[nt][j];
            }
    }
}

extern "C" void kernel_launch(void* const* d_in, const int* in_sizes, int n_in,
                              void* d_out, int out_size, void* d_ws, size_t ws_size,
                              hipStream_t stream) {
    const float* left      = (const float*)d_in[0];
    const int*   ei        = (const int*)d_in[1];
    const float* efeat     = (const float*)d_in[2];
    const float* right     = (const float*)d_in[3];
    const float* W_lin     = (const float*)d_in[5];
    const float* att_src   = (const float*)d_in[6];
    const float* att_dst   = (const float*)d_in[7];
    const float* W_edge    = (const float*)d_in[8];
    const float* att_edge  = (const float*)d_in[9];
    const float* bias_conv = (const float*)d_in[10];
    const float* W_lt      = (const float*)d_in[11];
    const float* b_lt      = (const float*)d_in[12];
    const float* W_fm      = (const float*)d_in[13];
    const float* b_fm      = (const float*)d_in[14];
    const float* W_pc      = (const float*)d_in[15];
    const float* b_pc      = (const float*)d_in[16];

    const int N = in_sizes[0] / DD;     // 50000
    const int E = in_sizes[2] / DD;     // 800000
    const int NB = (N + 255) / 256;     // 196 scan blocks (must be <= 256)

    // ws layout (4B units):
    //   vfold 512 | a_src 2N | a_dst 2N | counts N | offs N | cursor N |
    //   bsum 256 | bpre 256 | payload 4E (16B-aligned) | agg 128N   (~43 MB)
    float* ws     = (float*)d_ws;
    float* vfold  = ws;
    float* a_src  = ws + 512;
    float* a_dst  = a_src + 2 * (size_t)N;
    int*   counts = (int*)(a_dst + 2 * (size_t)N);
    int*   offs   = counts + N;
    int*   cursor = offs + N;
    int*   bsum   = cursor + N;
    int*   bpre   = bsum + 256;
    size_t po     = ((size_t)(1024 + 7 * (size_t)N) + 3) & ~(size_t)3;
    float4* payload = (float4*)(ws + po);
    float* agg    = ws + po + 4 * (size_t)E;
    (void)ws_size; (void)n_in; (void)out_size;

    float* out_lu   = (float*)d_out;                 // [N,64]
    float* out_ei   = out_lu + (size_t)N * CC;       // [2,E] as float
    float* att_slot = out_ei + (size_t)2 * E;        // [E,2]: alpha -> att

    hipMemsetAsync(counts, 0, (size_t)N * sizeof(int), stream);

    hipLaunchKernelGGL(k_fold, dim3(1), dim3(128), 0, stream,
                       W_lin, att_src, att_dst, W_edge, att_edge, vfold);
    hipLaunchKernelGGL(k_node_logits, dim3((N + 63) / 64), dim3(256), 0, stream,
                       right, left, vfold, a_src, a_dst, N);
    hipLaunchKernelGGL(k_edge_alpha, dim3((E + 63) / 64), dim3(256), 0, stream,
                       efeat, ei, vfold, a_src, a_dst, att_slot, counts, out_ei,
                       E, N);
    hipLaunchKernelGGL(k_scan1, dim3(NB), dim3(256), 0, stream,
                       counts, bsum, N);
    hipLaunchKernelGGL(k_scan2, dim3(1), dim3(256), 0, stream,
                       bsum, bpre, NB);
    hipLaunchKernelGGL(k_scan3, dim3(NB), dim3(256), 0, stream,
                       counts, bpre, offs, cursor, N);
    hipLaunchKernelGGL(k_ids, dim3((E + 255) / 256), dim3(256), 0, stream,
                       ei, att_slot, cursor, payload, E, N);
    hipLaunchKernelGGL(k_gather, dim3((N + 15) / 16), dim3(256), 0, stream,
                       payload, offs, counts, right, att_slot, agg, N);
    hipLaunchKernelGGL(k_lin_mfma, dim3(512), dim3(256), 0, stream,
                       W_lin, bias_conv, agg, N);
    hipLaunchKernelGGL(k_tail_mfma, dim3(512), dim3(256), 0, stream,
                       agg, left, W_lt, b_lt, W_fm, b_fm, W_pc, b_pc, out_lu, N);
}